// Round 4
// baseline (1739.225 us; speedup 1.0000x reference)
//
#include <hip/hip_runtime.h>

// GINe forward: N=50000 nodes, E=500000 edges, H=128, L=2 layers, C=2.
// World model (round-3 resolution): ALL float inputs fp32, edge_index int32,
// OUTPUT fp32 [E,2]. (Threshold 4.875e-2 == 2% * max|ref| => fp32 mode; the
// "(bf16" in the harness label is boilerplate.) Runtime dtype detection kept
// as cheap insurance. Internal compute: f16 MFMA (16x16x32), f32 accumulate.

#define NN 50000
#define NE 500000
#define HD 128

typedef _Float16 f16;
typedef _Float16 f16x8 __attribute__((ext_vector_type(8)));
typedef _Float16 f16x4 __attribute__((ext_vector_type(4)));
typedef _Float16 f16x2 __attribute__((ext_vector_type(2)));
typedef float f32x4 __attribute__((ext_vector_type(4)));
typedef unsigned short ushort_t;

#define MFMA16(a, b, c) __builtin_amdgcn_mfma_f32_16x16x32_f16((a), (b), (c), 0, 0, 0)

// t-tile LDS row stride (f16): 152*2=304 B -> 16B-aligned rows, <=2-way bank
// conflict on ds_read_b128 (free per m136).
#define TSTR 152

// f32 param blob offsets (element units)
#define P_NODE_W 0
#define P_NODE_B 16384
#define P_EDGE_W 16512
#define P_EDGE_B 18560
#define P_CONV_W1 18688
#define P_CONV_B1 51456
#define P_CONV_W2 51712
#define P_CONV_B2 84480
#define P_GAMMA 84736
#define P_BETA 84992
#define P_EMLP_W1 85248
#define P_EMLP_B1 183552
#define P_EMLP_W2 183808
#define P_EMLP_B2 216576
#define P_MLP_W1 216832
#define P_MLP_B1 236032
#define P_MLP_W2 236082
#define P_MLP_B2 237332
#define P_MLP_W3 237357
#define P_MLP_B3 237407
#define P_TOTAL 237409

__device__ __forceinline__ float bf2f(unsigned short u) {
    union { unsigned int i; float f; } v;
    v.i = ((unsigned int)u) << 16;
    return v.f;
}

// ---------------------------------------------------------------------------
// Detect input dtypes. flags[0]=1 -> floats are fp32 (else bf16).
// flags[1]=1 -> edge_index is int64 (else int32).
// ---------------------------------------------------------------------------
__global__ __launch_bounds__(256) void k_detect(
    const unsigned int* nw, const int* ei, int* flags) {
    __shared__ int cF, cI;
    if (threadIdx.x == 0) { cF = 0; cI = 0; }
    __syncthreads();
    unsigned int u = nw[threadIdx.x];            // 1 KB read: safe in both worlds
    int e = (int)((u >> 7) & 0xFFu);             // exp field of low-u16-as-bf16
    int odd = ei[2 * threadIdx.x + 1];           // 2 KB read: safe in both worlds
    if (e >= 100 && e <= 140) atomicAdd(&cF, 1);
    if (odd != 0) atomicAdd(&cI, 1);
    __syncthreads();
    if (threadIdx.x == 0) {
        flags[0] = (cF < 160) ? 1 : 0;
        flags[1] = (cI < 64) ? 1 : 0;
    }
}

// ---------------------------------------------------------------------------
// Convert a float array (fp32 or bf16 per flag) to f16, 4 elems/thread.
// ---------------------------------------------------------------------------
__global__ __launch_bounds__(256) void k_cvt(
    const void* src, f16* dst, int n4, const int* flags) {
    int i = blockIdx.x * 256 + threadIdx.x;
    if (i >= n4) return;
    f16x4 o;
    if (flags[0]) {
        float4 v = ((const float4*)src)[i];
        o[0] = (f16)v.x; o[1] = (f16)v.y; o[2] = (f16)v.z; o[3] = (f16)v.w;
    } else {
        ushort4 v = ((const ushort4*)src)[i];
        o[0] = (f16)bf2f(v.x); o[1] = (f16)bf2f(v.y);
        o[2] = (f16)bf2f(v.z); o[3] = (f16)bf2f(v.w);
    }
    ((f16x4*)dst)[i] = o;
}

// ---------------------------------------------------------------------------
// Convert all 20 weight/bias arrays into one f32 blob.
// ---------------------------------------------------------------------------
__global__ __launch_bounds__(256) void k_cvt_prm(
    const void* p0, const void* p1, const void* p2, const void* p3,
    const void* p4, const void* p5, const void* p6, const void* p7,
    const void* p8, const void* p9, const void* p10, const void* p11,
    const void* p12, const void* p13, const void* p14, const void* p15,
    const void* p16, const void* p17, const void* p18, const void* p19,
    float* prm, const int* flags) {
    int i = blockIdx.x * 256 + threadIdx.x;
    if (i >= P_TOTAL) return;
    const int offs[21] = {P_NODE_W, P_NODE_B, P_EDGE_W, P_EDGE_B, P_CONV_W1,
                          P_CONV_B1, P_CONV_W2, P_CONV_B2, P_GAMMA, P_BETA,
                          P_EMLP_W1, P_EMLP_B1, P_EMLP_W2, P_EMLP_B2, P_MLP_W1,
                          P_MLP_B1, P_MLP_W2, P_MLP_B2, P_MLP_W3, P_MLP_B3,
                          P_TOTAL};
    const void* srcs[20] = {p0, p1, p2, p3, p4, p5, p6, p7, p8, p9, p10, p11,
                            p12, p13, p14, p15, p16, p17, p18, p19};
    int s = 0;
#pragma unroll
    for (int k = 1; k < 20; ++k)
        if (i >= offs[k]) s = k;
    int li = i - offs[s];
    float v = flags[0] ? ((const float*)srcs[s])[li]
                       : bf2f(((const ushort_t*)srcs[s])[li]);
    prm[i] = v;
}

// ---------------------------------------------------------------------------
// Canonicalize edge_index to int32[2E].
// ---------------------------------------------------------------------------
__global__ __launch_bounds__(256) void k_cvt_idx(
    const int* src, int* dst, const int* flags) {
    int i = blockIdx.x * 256 + threadIdx.x;
    if (i >= 2 * NE) return;
    dst[i] = flags[1] ? src[2 * i] : src[i];
}

// ---------------------------------------------------------------------------
// Prep: swizzle all MFMA weight matrices (from f32 blob) into B-fragment order.
// elem index = fb*512 + (q*16+n)*8 + j, fb = nt*4+kt, holds W[kt*32+q*8+j][nt*16+n].
// wbuf slots: [0]=node_w, [1,2]=conv_w1 L0/L1, [3,4]=conv_w2, [5..10]=emlp_w1
// (l*3+seg), [11,12]=emlp_w2, then 3x8192 mlp_w1 (50->64 col pad).
// ---------------------------------------------------------------------------
__global__ __launch_bounds__(256) void k_prep(const float* prm, f16* wbuf) {
    int gid = blockIdx.x * 256 + threadIdx.x;
    if (gid < 13 * 16384) {
        int seg = gid >> 14;
        int idx = gid & 16383;
        int off;
        switch (seg) {
            case 0: off = P_NODE_W; break;
            case 1: off = P_CONV_W1; break;
            case 2: off = P_CONV_W1 + 16384; break;
            case 3: off = P_CONV_W2; break;
            case 4: off = P_CONV_W2 + 16384; break;
            case 5: case 6: case 7: off = P_EMLP_W1 + (seg - 5) * 16384; break;
            case 8: case 9: case 10: off = P_EMLP_W1 + 49152 + (seg - 8) * 16384; break;
            case 11: off = P_EMLP_W2; break;
            default: off = P_EMLP_W2 + 16384; break;
        }
        int fb = idx >> 9;
        int sub = (idx & 511) >> 3;
        int j = idx & 7;
        int q = sub >> 4, n = sub & 15;
        int nt = fb >> 2, kt = fb & 3;
        int k = kt * 32 + q * 8 + j;
        int c = nt * 16 + n;
        wbuf[gid] = (f16)prm[off + k * 128 + c];
    } else {
        int t = gid - 13 * 16384;
        if (t >= 3 * 8192) return;
        int s = t >> 13;
        int idx = t & 8191;
        int fb = idx >> 9;
        int sub = (idx & 511) >> 3;
        int j = idx & 7;
        int q = sub >> 4, n = sub & 15;
        int nt = fb >> 2, kt = fb & 3;
        int k = s * 128 + kt * 32 + q * 8 + j;   // 0..383
        int c = nt * 16 + n;                     // 0..63 (pad >=50 with 0)
        float v = (c < 50) ? prm[P_MLP_W1 + k * 50 + c] : 0.f;
        wbuf[13 * 16384 + s * 8192 + idx] = (f16)v;
    }
}

// ---------------------------------------------------------------------------
// h = x @ node_w + node_b -> h_f16.  Block: 128 rows, wave: 32 rows x 128 cols.
// ---------------------------------------------------------------------------
__global__ __launch_bounds__(256) void k_node_lin(
    const f16* xc, const f16* wT, const float* bias, f16* h_f16) {
    __shared__ __align__(16) f16 wlds[16384];
    int tid = threadIdx.x;
    {
        const uint4* s = (const uint4*)wT;
        uint4* d = (uint4*)wlds;
        for (int i = tid; i < 2048; i += 256) d[i] = s[i];
    }
    __syncthreads();
    int wave = tid >> 6, lane = tid & 63, q = lane >> 4, ln = lane & 15;
    int rowbase = blockIdx.x * 128 + wave * 32;
    f32x4 acc[2][8] = {};
    for (int kt = 0; kt < 4; ++kt) {
        int koff = kt * 32 + q * 8;
        f16x8 a[2];
#pragma unroll
        for (int mt = 0; mt < 2; ++mt) {
            int row = min(rowbase + mt * 16 + ln, NN - 1);
            a[mt] = *(const f16x8*)(xc + row * HD + koff);
        }
#pragma unroll
        for (int nt = 0; nt < 8; ++nt) {
            f16x8 b = *(const f16x8*)&wlds[(nt * 4 + kt) * 512 + lane * 8];
            acc[0][nt] = MFMA16(a[0], b, acc[0][nt]);
            acc[1][nt] = MFMA16(a[1], b, acc[1][nt]);
        }
    }
#pragma unroll
    for (int nt = 0; nt < 8; ++nt) {
        int col = nt * 16 + ln;
        float bv = bias[col];
#pragma unroll
        for (int mt = 0; mt < 2; ++mt)
#pragma unroll
            for (int r = 0; r < 4; ++r) {
                int row = rowbase + mt * 16 + q * 4 + r;
                if (row < NN) h_f16[row * HD + col] = (f16)(acc[mt][nt][r] + bv);
            }
    }
}

// ---------------------------------------------------------------------------
// ea = edge_attr @ edge_w + edge_b  (K=16 -> VALU). Block: 64 edges.
// ---------------------------------------------------------------------------
__global__ __launch_bounds__(256) void k_edge_lin(
    const f16* eattr, const float* ew, const float* ebias, f16* ea) {
    __shared__ float wl[16 * 128];
    __shared__ float bl[128];
    __shared__ float al[64 * 16];
    int tid = threadIdx.x;
    int eb = blockIdx.x * 64;
    for (int i = tid; i < 2048; i += 256) wl[i] = ew[i];
    if (tid < 128) bl[tid] = ebias[tid];
    {
        int e_l = tid >> 2, k0 = (tid & 3) * 4;
        int e = min(eb + e_l, NE - 1);
        f16x4 u = *(const f16x4*)(eattr + e * 16 + k0);
        al[e_l * 16 + k0 + 0] = (float)u[0];
        al[e_l * 16 + k0 + 1] = (float)u[1];
        al[e_l * 16 + k0 + 2] = (float)u[2];
        al[e_l * 16 + k0 + 3] = (float)u[3];
    }
    __syncthreads();
    for (int i = 0; i < 32; ++i) {
        int o = i * 256 + tid;
        int e_l = o >> 7, c = o & 127;
        float s = bl[c];
#pragma unroll
        for (int k = 0; k < 16; ++k) s += al[e_l * 16 + k] * wl[k * 128 + c];
        int e = eb + e_l;
        if (e < NE) ea[(size_t)e * HD + c] = (f16)s;
    }
}

// ---------------------------------------------------------------------------
// msg = relu(h[src] + ea); agg[dst] += msg.  One wave per edge (loop of 8).
// ---------------------------------------------------------------------------
__global__ __launch_bounds__(256) void k_msg(
    const f16* ea, const f16* h16, const int* eidx, float* agg) {
    int wid = (blockIdx.x * 256 + threadIdx.x) >> 6;
    int lane = threadIdx.x & 63;
    int e0 = wid * 8;
    for (int i = 0; i < 8; ++i) {
        int e = e0 + i;
        if (e >= NE) return;
        int s = eidx[e], d = eidx[NE + e];
        f16x2 ev = *(const f16x2*)(ea + (size_t)e * HD + lane * 2);
        f16x2 hv = *(const f16x2*)(h16 + (size_t)s * HD + lane * 2);
        float m0 = fmaxf((float)ev[0] + (float)hv[0], 0.f);
        float m1 = fmaxf((float)ev[1] + (float)hv[1], 0.f);
        atomicAdd(&agg[d * HD + lane * 2], m0);
        atomicAdd(&agg[d * HD + lane * 2 + 1], m1);
    }
}

// ---------------------------------------------------------------------------
// t_node = relu((h + agg) @ conv_w1 + b1)
// ---------------------------------------------------------------------------
__global__ __launch_bounds__(256) void k_conv1(
    const f16* h16, const float* agg, const f16* wT, const float* bias,
    f16* t_node) {
    __shared__ __align__(16) f16 wlds[16384];
    int tid = threadIdx.x;
    {
        const uint4* s = (const uint4*)wT;
        uint4* d = (uint4*)wlds;
        for (int i = tid; i < 2048; i += 256) d[i] = s[i];
    }
    __syncthreads();
    int wave = tid >> 6, lane = tid & 63, q = lane >> 4, ln = lane & 15;
    int rowbase = blockIdx.x * 128 + wave * 32;
    f32x4 acc[2][8] = {};
    for (int kt = 0; kt < 4; ++kt) {
        int koff = kt * 32 + q * 8;
        f16x8 a[2];
#pragma unroll
        for (int mt = 0; mt < 2; ++mt) {
            int row = min(rowbase + mt * 16 + ln, NN - 1);
            f16x8 hv = *(const f16x8*)(h16 + row * HD + koff);
            const float4* gp = (const float4*)(agg + row * HD + koff);
            float4 g0 = gp[0], g1 = gp[1];
            f16x8 av;
            av[0] = (f16)((float)hv[0] + g0.x); av[1] = (f16)((float)hv[1] + g0.y);
            av[2] = (f16)((float)hv[2] + g0.z); av[3] = (f16)((float)hv[3] + g0.w);
            av[4] = (f16)((float)hv[4] + g1.x); av[5] = (f16)((float)hv[5] + g1.y);
            av[6] = (f16)((float)hv[6] + g1.z); av[7] = (f16)((float)hv[7] + g1.w);
            a[mt] = av;
        }
#pragma unroll
        for (int nt = 0; nt < 8; ++nt) {
            f16x8 b = *(const f16x8*)&wlds[(nt * 4 + kt) * 512 + lane * 8];
            acc[0][nt] = MFMA16(a[0], b, acc[0][nt]);
            acc[1][nt] = MFMA16(a[1], b, acc[1][nt]);
        }
    }
#pragma unroll
    for (int nt = 0; nt < 8; ++nt) {
        int col = nt * 16 + ln;
        float bv = bias[col];
#pragma unroll
        for (int mt = 0; mt < 2; ++mt)
#pragma unroll
            for (int r = 0; r < 4; ++r) {
                int row = rowbase + mt * 16 + q * 4 + r;
                if (row < NN)
                    t_node[row * HD + col] = (f16)fmaxf(acc[mt][nt][r] + bv, 0.f);
            }
    }
}

// ---------------------------------------------------------------------------
// z2 = t_node @ conv_w2 + b2 (store f16) + BN partial stats (f32 sum, sumsq)
// ---------------------------------------------------------------------------
__global__ __launch_bounds__(256) void k_conv2(
    const f16* t_node, const f16* wT, const float* bias, f16* z2, float* stats) {
    __shared__ __align__(16) f16 wlds[16384];
    int tid = threadIdx.x;
    {
        const uint4* s = (const uint4*)wT;
        uint4* d = (uint4*)wlds;
        for (int i = tid; i < 2048; i += 256) d[i] = s[i];
    }
    __syncthreads();
    int wave = tid >> 6, lane = tid & 63, q = lane >> 4, ln = lane & 15;
    int rowbase = blockIdx.x * 128 + wave * 32;
    f32x4 acc[2][8] = {};
    for (int kt = 0; kt < 4; ++kt) {
        int koff = kt * 32 + q * 8;
        f16x8 a[2];
#pragma unroll
        for (int mt = 0; mt < 2; ++mt) {
            int row = min(rowbase + mt * 16 + ln, NN - 1);
            a[mt] = *(const f16x8*)(t_node + row * HD + koff);
        }
#pragma unroll
        for (int nt = 0; nt < 8; ++nt) {
            f16x8 b = *(const f16x8*)&wlds[(nt * 4 + kt) * 512 + lane * 8];
            acc[0][nt] = MFMA16(a[0], b, acc[0][nt]);
            acc[1][nt] = MFMA16(a[1], b, acc[1][nt]);
        }
    }
#pragma unroll
    for (int nt = 0; nt < 8; ++nt) {
        int col = nt * 16 + ln;
        float bv = bias[col];
        float s = 0.f, s2 = 0.f;
#pragma unroll
        for (int mt = 0; mt < 2; ++mt)
#pragma unroll
            for (int r = 0; r < 4; ++r) {
                int row = rowbase + mt * 16 + q * 4 + r;
                if (row < NN) {
                    float v = acc[mt][nt][r] + bv;
                    z2[row * HD + col] = (f16)v;
                    s += v;
                    s2 += v * v;
                }
            }
        s += __shfl_xor(s, 16);  s += __shfl_xor(s, 32);
        s2 += __shfl_xor(s2, 16); s2 += __shfl_xor(s2, 32);
        if (lane < 16) {
            atomicAdd(&stats[col], s);
            atomicAdd(&stats[HD + col], s2);
        }
    }
}

// ---------------------------------------------------------------------------
// BN apply + residual: h = (h + relu(gamma*(z2-mu)*rsqrt(var+eps)+beta)) * 0.5
// ---------------------------------------------------------------------------
__global__ __launch_bounds__(256) void k_bn(
    const f16* z2, const float* stats, const float* gamma, const float* beta,
    f16* h16) {
    int gid = blockIdx.x * 256 + threadIdx.x;
    if (gid >= NN * HD / 4) return;
    int base = gid * 4;
    int c0 = base & (HD - 1);
    f16x4 z = *(const f16x4*)(z2 + base);
    f16x4 h = *(const f16x4*)(h16 + base);
    f16x4 ho;
#pragma unroll
    for (int j = 0; j < 4; ++j) {
        int c = c0 + j;
        float mu = stats[c] * (1.0f / NN);
        float var = stats[HD + c] * (1.0f / NN) - mu * mu;
        float zn = gamma[c] * ((float)z[j] - mu) * rsqrtf(var + 1e-5f) + beta[c];
        ho[j] = (f16)(((float)h[j] + fmaxf(zn, 0.f)) * 0.5f);
    }
    *(f16x4*)(h16 + base) = ho;
}

// ---------------------------------------------------------------------------
// Fused edge MLP: ea += 0.5*(relu([h_src|h_dst|ea]@W1+b1)@W2+b2).
// Block = 128 edges; t tile in LDS. Wave: 32 edges x 128 cols.
// ---------------------------------------------------------------------------
__global__ __launch_bounds__(256) void k_emlp(
    const f16* h16, const int* eidx, const f16* w1T, const float* b1,
    const f16* w2T, const float* b2, f16* ea) {
    __shared__ __align__(16) f16 wlds[16384];
    __shared__ __align__(16) f16 t16[128 * TSTR];
    __shared__ int sidx[128], didx[128];
    int tid = threadIdx.x;
    int eb = blockIdx.x * 128;
    if (tid < 128) {
        int e = min(eb + tid, NE - 1);
        sidx[tid] = eidx[e];
        didx[tid] = eidx[NE + e];
    }
    int wave = tid >> 6, lane = tid & 63, q = lane >> 4, ln = lane & 15;
    f32x4 acc[2][8] = {};
    for (int seg = 0; seg < 3; ++seg) {
        __syncthreads();
        {
            const uint4* s = (const uint4*)(w1T + seg * 16384);
            uint4* d = (uint4*)wlds;
            for (int i = tid; i < 2048; i += 256) d[i] = s[i];
        }
        __syncthreads();
        for (int kt = 0; kt < 4; ++kt) {
            int koff = kt * 32 + q * 8;
            f16x8 a[2];
#pragma unroll
            for (int mt = 0; mt < 2; ++mt) {
                int le = wave * 32 + mt * 16 + ln;
                const f16* ap;
                if (seg == 0)      ap = h16 + (size_t)sidx[le] * HD + koff;
                else if (seg == 1) ap = h16 + (size_t)didx[le] * HD + koff;
                else               ap = ea + (size_t)min(eb + le, NE - 1) * HD + koff;
                a[mt] = *(const f16x8*)ap;
            }
#pragma unroll
            for (int nt = 0; nt < 8; ++nt) {
                f16x8 b = *(const f16x8*)&wlds[(nt * 4 + kt) * 512 + lane * 8];
                acc[0][nt] = MFMA16(a[0], b, acc[0][nt]);
                acc[1][nt] = MFMA16(a[1], b, acc[1][nt]);
            }
        }
    }
#pragma unroll
    for (int nt = 0; nt < 8; ++nt) {
        int col = nt * 16 + ln;
        float bv = b1[col];
#pragma unroll
        for (int mt = 0; mt < 2; ++mt)
#pragma unroll
            for (int r = 0; r < 4; ++r) {
                int row = wave * 32 + mt * 16 + q * 4 + r;
                t16[row * TSTR + col] = (f16)fmaxf(acc[mt][nt][r] + bv, 0.f);
            }
    }
    __syncthreads();
    {
        const uint4* s = (const uint4*)w2T;
        uint4* d = (uint4*)wlds;
        for (int i = tid; i < 2048; i += 256) d[i] = s[i];
    }
    __syncthreads();
    f32x4 acc2[2][8] = {};
    for (int kt = 0; kt < 4; ++kt) {
        int koff = kt * 32 + q * 8;
        f16x8 a[2];
#pragma unroll
        for (int mt = 0; mt < 2; ++mt) {
            int le = wave * 32 + mt * 16 + ln;
            a[mt] = *(const f16x8*)&t16[le * TSTR + koff];
        }
#pragma unroll
        for (int nt = 0; nt < 8; ++nt) {
            f16x8 b = *(const f16x8*)&wlds[(nt * 4 + kt) * 512 + lane * 8];
            acc2[0][nt] = MFMA16(a[0], b, acc2[0][nt]);
            acc2[1][nt] = MFMA16(a[1], b, acc2[1][nt]);
        }
    }
#pragma unroll
    for (int nt = 0; nt < 8; ++nt) {
        int col = nt * 16 + ln;
        float bv = b2[col];
#pragma unroll
        for (int mt = 0; mt < 2; ++mt)
#pragma unroll
            for (int r = 0; r < 4; ++r) {
                int e = eb + wave * 32 + mt * 16 + q * 4 + r;
                if (e < NE) {
                    size_t o = (size_t)e * HD + col;
                    ea[o] = (f16)((float)ea[o] + 0.5f * (acc2[mt][nt][r] + bv));
                }
            }
    }
}

// ---------------------------------------------------------------------------
// Readout: feat=[h_src|h_dst|ea] -> relu(@w1+b1)[50] -> relu(@w2+b2)[25] -> @w3+b3[2]
// Output fp32 [E,2].
// ---------------------------------------------------------------------------
__global__ __launch_bounds__(256) void k_readout(
    const f16* h16, const f16* ea, const int* eidx, const f16* w1Tp,
    const float* mb1, const float* mw2, const float* mb2,
    const float* mw3, const float* mb3, float* out) {
    __shared__ __align__(16) f16 wlds[8192];
    __shared__ f16 o1[256 * 58];
    __shared__ float w2l[50 * 28];
    __shared__ float w3l[50];
    __shared__ float b2l[25];
    __shared__ float b3l[2];
    __shared__ int sidx[256], didx[256];
    int tid = threadIdx.x;
    int eb = blockIdx.x * 256;
    {
        int e = min(eb + tid, NE - 1);
        sidx[tid] = eidx[e];
        didx[tid] = eidx[NE + e];
    }
    for (int i = tid; i < 50 * 28; i += 256) {
        int k = i / 28, ko = i - k * 28;
        w2l[i] = (ko < 25) ? mw2[k * 25 + ko] : 0.f;
    }
    if (tid < 50) w3l[tid] = mw3[tid];
    if (tid < 25) b2l[tid] = mb2[tid];
    if (tid < 2) b3l[tid] = mb3[tid];
    int wave = tid >> 6, lane = tid & 63, q = lane >> 4, ln = lane & 15;
    f32x4 acc[4][4] = {};
    for (int seg = 0; seg < 3; ++seg) {
        __syncthreads();
        {
            const uint4* s = (const uint4*)(w1Tp + seg * 8192);
            uint4* d = (uint4*)wlds;
            for (int i = tid; i < 1024; i += 256) d[i] = s[i];
        }
        __syncthreads();
        for (int kt = 0; kt < 4; ++kt) {
            int koff = kt * 32 + q * 8;
            f16x8 a[4];
#pragma unroll
            for (int mt = 0; mt < 4; ++mt) {
                int le = wave * 64 + mt * 16 + ln;
                const f16* ap;
                if (seg == 0)      ap = h16 + (size_t)sidx[le] * HD + koff;
                else if (seg == 1) ap = h16 + (size_t)didx[le] * HD + koff;
                else               ap = ea + (size_t)min(eb + le, NE - 1) * HD + koff;
                a[mt] = *(const f16x8*)ap;
            }
#pragma unroll
            for (int nt = 0; nt < 4; ++nt) {
                f16x8 b = *(const f16x8*)&wlds[(nt * 4 + kt) * 512 + lane * 8];
#pragma unroll
                for (int mt = 0; mt < 4; ++mt)
                    acc[mt][nt] = MFMA16(a[mt], b, acc[mt][nt]);
            }
        }
    }
#pragma unroll
    for (int nt = 0; nt < 4; ++nt) {
        int col = nt * 16 + ln;
        if (col < 50) {
            float bv = mb1[col];
#pragma unroll
            for (int mt = 0; mt < 4; ++mt)
#pragma unroll
                for (int r = 0; r < 4; ++r) {
                    int le = wave * 64 + mt * 16 + q * 4 + r;
                    o1[le * 58 + col] = (f16)fmaxf(acc[mt][nt][r] + bv, 0.f);
                }
        }
    }
    __syncthreads();
    float o2[25];
#pragma unroll
    for (int ko = 0; ko < 25; ++ko) o2[ko] = b2l[ko];
    for (int k = 0; k < 50; ++k) {
        float a = (float)o1[tid * 58 + k];
#pragma unroll
        for (int ko = 0; ko < 25; ++ko) o2[ko] += a * w2l[k * 28 + ko];
    }
    float r0 = b3l[0], r1 = b3l[1];
#pragma unroll
    for (int ko = 0; ko < 25; ++ko) {
        float a = fmaxf(o2[ko], 0.f);
        r0 += a * w3l[ko * 2];
        r1 += a * w3l[ko * 2 + 1];
    }
    int e = eb + tid;
    if (e < NE) {
        float2 o; o.x = r0; o.y = r1;
        *(float2*)(out + (size_t)e * 2) = o;    // fp32 output, 8B store
    }
}

// ---------------------------------------------------------------------------
extern "C" void kernel_launch(void* const* d_in, const int* in_sizes, int n_in,
                              void* d_out, int out_size, void* d_ws, size_t ws_size,
                              hipStream_t stream) {
    // ws layout (bytes):
    //   ea      : 0            .. 128,000,000  (f16 E*128)
    //   hf16    : 128,000,000  .. 140,800,000  (f16 N*128)
    //   agg     : 140,800,000  .. 166,400,000  (f32 N*128)  [alias: eattr16 16MB]
    //   z2      : 166,400,000  .. 179,200,000  (f16 N*128)  [alias: xc 12.8MB]
    //   tn      : 179,200,000  .. 192,000,000  (f16 N*128)
    //   wbuf    : 192,000,000  .. 192,475,136  (f16 237,568)
    //   stats   : 192,475,136  .. 192,476,160
    //   prm     : 192,476,160  .. 193,425,796  (f32 237,409)
    //   eix     : 193,425,920  .. 197,425,920  (i32 2E)
    //   flags   : 197,425,920  .. 197,425,936
    const size_t WS_NEED = 197425936ULL;
    if (ws_size < WS_NEED) {
        hipMemsetAsync(d_out, 0, (size_t)out_size * 4, stream);
        return;
    }
    char* ws = (char*)d_ws;
    f16* ea = (f16*)(ws);
    f16* hf16 = (f16*)(ws + 128000000LL);
    float* agg = (float*)(ws + 140800000LL);
    f16* eattr16 = (f16*)(ws + 140800000LL);   // alias agg (dead before k_msg)
    f16* z2 = (f16*)(ws + 166400000LL);
    f16* xc = (f16*)(ws + 166400000LL);        // alias z2 (dead before k_conv2)
    f16* tn = (f16*)(ws + 179200000LL);
    f16* wbuf = (f16*)(ws + 192000000LL);
    float* stats = (float*)(ws + 192475136LL);
    float* prm = (float*)(ws + 192476160LL);
    int* eix = (int*)(ws + 193425920LL);
    int* flags = (int*)(ws + 197425920LL);
    float* out = (float*)d_out;

    k_detect<<<1, 256, 0, stream>>>((const unsigned int*)d_in[2],
                                    (const int*)d_in[22], flags);
    k_cvt<<<6250, 256, 0, stream>>>(d_in[0], xc, 1600000, flags);
    k_cvt<<<7813, 256, 0, stream>>>(d_in[1], eattr16, 2000000, flags);
    k_cvt_prm<<<928, 256, 0, stream>>>(
        d_in[2], d_in[3], d_in[4], d_in[5], d_in[6], d_in[7], d_in[8], d_in[9],
        d_in[10], d_in[11], d_in[12], d_in[13], d_in[14], d_in[15], d_in[16],
        d_in[17], d_in[18], d_in[19], d_in[20], d_in[21], prm, flags);
    k_cvt_idx<<<3907, 256, 0, stream>>>((const int*)d_in[22], eix, flags);

    k_prep<<<928, 256, 0, stream>>>(prm, wbuf);
    k_node_lin<<<391, 256, 0, stream>>>(xc, wbuf, prm + P_NODE_B, hf16);
    k_edge_lin<<<7813, 256, 0, stream>>>(eattr16, prm + P_EDGE_W, prm + P_EDGE_B, ea);

    for (int l = 0; l < 2; ++l) {
        hipMemsetAsync(agg, 0, (size_t)NN * HD * 4, stream);
        hipMemsetAsync(stats, 0, 1024, stream);
        k_msg<<<15625, 256, 0, stream>>>(ea, hf16, eix, agg);
        k_conv1<<<391, 256, 0, stream>>>(hf16, agg, wbuf + (1 + l) * 16384,
                                         prm + P_CONV_B1 + l * HD, tn);
        k_conv2<<<391, 256, 0, stream>>>(tn, wbuf + (3 + l) * 16384,
                                         prm + P_CONV_B2 + l * HD, z2, stats);
        k_bn<<<6250, 256, 0, stream>>>(z2, stats, prm + P_GAMMA + l * HD,
                                       prm + P_BETA + l * HD, hf16);
        k_emlp<<<3907, 256, 0, stream>>>(hf16, eix, wbuf + (5 + l * 3) * 16384,
                                         prm + P_EMLP_B1 + l * HD,
                                         wbuf + (11 + l) * 16384,
                                         prm + P_EMLP_B2 + l * HD, ea);
    }
    k_readout<<<1954, 256, 0, stream>>>(hf16, ea, eix, wbuf + 13 * 16384,
                                        prm + P_MLP_B1, prm + P_MLP_W2,
                                        prm + P_MLP_B2, prm + P_MLP_W3,
                                        prm + P_MLP_B3, out);
}

// Round 5
// 1120.161 us; speedup vs baseline: 1.5527x; 1.5527x over previous
//
#include <hip/hip_runtime.h>

// GINe forward: N=50000 nodes, E=500000 edges, H=128, L=2 layers, C=2.
// fp32 inputs, int32 edge_index, fp32 output [E,2] (confirmed round 4).
// R5: replace atomic scatter-add aggregation (2x408us, atomic-bound) with
// CSR-gather (build CSR once, gather per layer). agg stored f16.

#define NN 50000
#define NE 500000
#define HD 128

typedef _Float16 f16;
typedef _Float16 f16x8 __attribute__((ext_vector_type(8)));
typedef _Float16 f16x4 __attribute__((ext_vector_type(4)));
typedef _Float16 f16x2 __attribute__((ext_vector_type(2)));
typedef float f32x4 __attribute__((ext_vector_type(4)));
typedef unsigned short ushort_t;

#define MFMA16(a, b, c) __builtin_amdgcn_mfma_f32_16x16x32_f16((a), (b), (c), 0, 0, 0)

#define TSTR 152

// f32 param blob offsets (element units)
#define P_NODE_W 0
#define P_NODE_B 16384
#define P_EDGE_W 16512
#define P_EDGE_B 18560
#define P_CONV_W1 18688
#define P_CONV_B1 51456
#define P_CONV_W2 51712
#define P_CONV_B2 84480
#define P_GAMMA 84736
#define P_BETA 84992
#define P_EMLP_W1 85248
#define P_EMLP_B1 183552
#define P_EMLP_W2 183808
#define P_EMLP_B2 216576
#define P_MLP_W1 216832
#define P_MLP_B1 236032
#define P_MLP_W2 236082
#define P_MLP_B2 237332
#define P_MLP_W3 237357
#define P_MLP_B3 237407
#define P_TOTAL 237409

__device__ __forceinline__ float bf2f(unsigned short u) {
    union { unsigned int i; float f; } v;
    v.i = ((unsigned int)u) << 16;
    return v.f;
}

// ---------------------------------------------------------------------------
__global__ __launch_bounds__(256) void k_detect(
    const unsigned int* nw, const int* ei, int* flags) {
    __shared__ int cF, cI;
    if (threadIdx.x == 0) { cF = 0; cI = 0; }
    __syncthreads();
    unsigned int u = nw[threadIdx.x];
    int e = (int)((u >> 7) & 0xFFu);
    int odd = ei[2 * threadIdx.x + 1];
    if (e >= 100 && e <= 140) atomicAdd(&cF, 1);
    if (odd != 0) atomicAdd(&cI, 1);
    __syncthreads();
    if (threadIdx.x == 0) {
        flags[0] = (cF < 160) ? 1 : 0;
        flags[1] = (cI < 64) ? 1 : 0;
    }
}

__global__ __launch_bounds__(256) void k_cvt(
    const void* src, f16* dst, int n4, const int* flags) {
    int i = blockIdx.x * 256 + threadIdx.x;
    if (i >= n4) return;
    f16x4 o;
    if (flags[0]) {
        float4 v = ((const float4*)src)[i];
        o[0] = (f16)v.x; o[1] = (f16)v.y; o[2] = (f16)v.z; o[3] = (f16)v.w;
    } else {
        ushort4 v = ((const ushort4*)src)[i];
        o[0] = (f16)bf2f(v.x); o[1] = (f16)bf2f(v.y);
        o[2] = (f16)bf2f(v.z); o[3] = (f16)bf2f(v.w);
    }
    ((f16x4*)dst)[i] = o;
}

__global__ __launch_bounds__(256) void k_cvt_prm(
    const void* p0, const void* p1, const void* p2, const void* p3,
    const void* p4, const void* p5, const void* p6, const void* p7,
    const void* p8, const void* p9, const void* p10, const void* p11,
    const void* p12, const void* p13, const void* p14, const void* p15,
    const void* p16, const void* p17, const void* p18, const void* p19,
    float* prm, const int* flags) {
    int i = blockIdx.x * 256 + threadIdx.x;
    if (i >= P_TOTAL) return;
    const int offs[21] = {P_NODE_W, P_NODE_B, P_EDGE_W, P_EDGE_B, P_CONV_W1,
                          P_CONV_B1, P_CONV_W2, P_CONV_B2, P_GAMMA, P_BETA,
                          P_EMLP_W1, P_EMLP_B1, P_EMLP_W2, P_EMLP_B2, P_MLP_W1,
                          P_MLP_B1, P_MLP_W2, P_MLP_B2, P_MLP_W3, P_MLP_B3,
                          P_TOTAL};
    const void* srcs[20] = {p0, p1, p2, p3, p4, p5, p6, p7, p8, p9, p10, p11,
                            p12, p13, p14, p15, p16, p17, p18, p19};
    int s = 0;
#pragma unroll
    for (int k = 1; k < 20; ++k)
        if (i >= offs[k]) s = k;
    int li = i - offs[s];
    float v = flags[0] ? ((const float*)srcs[s])[li]
                       : bf2f(((const ushort_t*)srcs[s])[li]);
    prm[i] = v;
}

__global__ __launch_bounds__(256) void k_cvt_idx(
    const int* src, int* dst, const int* flags) {
    int i = blockIdx.x * 256 + threadIdx.x;
    if (i >= 2 * NE) return;
    dst[i] = flags[1] ? src[2 * i] : src[i];
}

// ---------------------------------------------------------------------------
// CSR build: hist -> 3-phase exclusive scan -> scatter permutation.
// ---------------------------------------------------------------------------
__global__ __launch_bounds__(256) void k_hist(const int* eix, int* cnt) {
    int e = blockIdx.x * 256 + threadIdx.x;
    if (e < NE) atomicAdd(&cnt[eix[NE + e]], 1);
}

__global__ __launch_bounds__(256) void k_scanA(const int* cnt, int* bsum) {
    __shared__ int wsum[4];
    int tid = threadIdx.x;
    int i = blockIdx.x * 256 + tid;
    int v = (i < NN) ? cnt[i] : 0;
#pragma unroll
    for (int s = 1; s < 64; s <<= 1) v += __shfl_xor(v, s);
    if ((tid & 63) == 0) wsum[tid >> 6] = v;
    __syncthreads();
    if (tid == 0) bsum[blockIdx.x] = wsum[0] + wsum[1] + wsum[2] + wsum[3];
}

__global__ __launch_bounds__(256) void k_scanB(const int* bsum, int* bpre, int* off) {
    __shared__ int l[200];
    int tid = threadIdx.x;
    if (tid < 196) l[tid] = bsum[tid];
    __syncthreads();
    if (tid == 0) {
        int run = 0;
        for (int b = 0; b < 196; ++b) { int t = l[b]; l[b] = run; run += t; }
        off[NN] = run;
    }
    __syncthreads();
    if (tid < 196) bpre[tid] = l[tid];
}

__global__ __launch_bounds__(256) void k_scanC(
    const int* cnt, const int* bpre, int* off, int* cursor) {
    __shared__ int wsum[4];
    int tid = threadIdx.x;
    int lane = tid & 63, wave = tid >> 6;
    int i = blockIdx.x * 256 + tid;
    int v = (i < NN) ? cnt[i] : 0;
    int incl = v;
#pragma unroll
    for (int s = 1; s < 64; s <<= 1) {
        int t = __shfl_up(incl, s);
        if (lane >= s) incl += t;
    }
    if (lane == 63) wsum[wave] = incl;
    __syncthreads();
    int add = bpre[blockIdx.x];
    for (int w = 0; w < 4; ++w)
        if (w < wave) add += wsum[w];
    int excl = add + incl - v;
    if (i < NN) { off[i] = excl; cursor[i] = excl; }
}

__global__ __launch_bounds__(256) void k_scatter(
    const int* eix, int* cursor, int* eord) {
    int e = blockIdx.x * 256 + threadIdx.x;
    if (e >= NE) return;
    int d = eix[NE + e];
    int pos = atomicAdd(&cursor[d], 1);
    eord[pos] = e;
}

// ---------------------------------------------------------------------------
// CSR gather: agg[n] = sum_{e in in(n)} relu(h[src[e]] + ea[e]).  One wave
// per node; lane owns channels 2l,2l+1; f32 accumulate, f16 store.
// ---------------------------------------------------------------------------
__global__ __launch_bounds__(256) void k_agg(
    const f16* ea, const f16* h16, const int* eix, const int* off,
    const int* eord, f16* agg16) {
    int wid = (blockIdx.x * 256 + threadIdx.x) >> 6;
    int lane = threadIdx.x & 63;
    int beg = off[wid], end = off[wid + 1];
    float a0 = 0.f, a1 = 0.f;
    for (int i = beg; i < end; ++i) {
        int e = eord[i];
        int s = eix[e];
        f16x2 ev = *(const f16x2*)(ea + (size_t)e * HD + lane * 2);
        f16x2 hv = *(const f16x2*)(h16 + (size_t)s * HD + lane * 2);
        a0 += fmaxf((float)ev[0] + (float)hv[0], 0.f);
        a1 += fmaxf((float)ev[1] + (float)hv[1], 0.f);
    }
    f16x2 o; o[0] = (f16)a0; o[1] = (f16)a1;
    *(f16x2*)(agg16 + (size_t)wid * HD + lane * 2) = o;
}

// ---------------------------------------------------------------------------
// Prep: swizzle all MFMA weight matrices into B-fragment order.
// ---------------------------------------------------------------------------
__global__ __launch_bounds__(256) void k_prep(const float* prm, f16* wbuf) {
    int gid = blockIdx.x * 256 + threadIdx.x;
    if (gid < 13 * 16384) {
        int seg = gid >> 14;
        int idx = gid & 16383;
        int off;
        switch (seg) {
            case 0: off = P_NODE_W; break;
            case 1: off = P_CONV_W1; break;
            case 2: off = P_CONV_W1 + 16384; break;
            case 3: off = P_CONV_W2; break;
            case 4: off = P_CONV_W2 + 16384; break;
            case 5: case 6: case 7: off = P_EMLP_W1 + (seg - 5) * 16384; break;
            case 8: case 9: case 10: off = P_EMLP_W1 + 49152 + (seg - 8) * 16384; break;
            case 11: off = P_EMLP_W2; break;
            default: off = P_EMLP_W2 + 16384; break;
        }
        int fb = idx >> 9;
        int sub = (idx & 511) >> 3;
        int j = idx & 7;
        int q = sub >> 4, n = sub & 15;
        int nt = fb >> 2, kt = fb & 3;
        int k = kt * 32 + q * 8 + j;
        int c = nt * 16 + n;
        wbuf[gid] = (f16)prm[off + k * 128 + c];
    } else {
        int t = gid - 13 * 16384;
        if (t >= 3 * 8192) return;
        int s = t >> 13;
        int idx = t & 8191;
        int fb = idx >> 9;
        int sub = (idx & 511) >> 3;
        int j = idx & 7;
        int q = sub >> 4, n = sub & 15;
        int nt = fb >> 2, kt = fb & 3;
        int k = s * 128 + kt * 32 + q * 8 + j;
        int c = nt * 16 + n;
        float v = (c < 50) ? prm[P_MLP_W1 + k * 50 + c] : 0.f;
        wbuf[13 * 16384 + s * 8192 + idx] = (f16)v;
    }
}

// ---------------------------------------------------------------------------
__global__ __launch_bounds__(256) void k_node_lin(
    const f16* xc, const f16* wT, const float* bias, f16* h_f16) {
    __shared__ __align__(16) f16 wlds[16384];
    int tid = threadIdx.x;
    {
        const uint4* s = (const uint4*)wT;
        uint4* d = (uint4*)wlds;
        for (int i = tid; i < 2048; i += 256) d[i] = s[i];
    }
    __syncthreads();
    int wave = tid >> 6, lane = tid & 63, q = lane >> 4, ln = lane & 15;
    int rowbase = blockIdx.x * 128 + wave * 32;
    f32x4 acc[2][8] = {};
    for (int kt = 0; kt < 4; ++kt) {
        int koff = kt * 32 + q * 8;
        f16x8 a[2];
#pragma unroll
        for (int mt = 0; mt < 2; ++mt) {
            int row = min(rowbase + mt * 16 + ln, NN - 1);
            a[mt] = *(const f16x8*)(xc + row * HD + koff);
        }
#pragma unroll
        for (int nt = 0; nt < 8; ++nt) {
            f16x8 b = *(const f16x8*)&wlds[(nt * 4 + kt) * 512 + lane * 8];
            acc[0][nt] = MFMA16(a[0], b, acc[0][nt]);
            acc[1][nt] = MFMA16(a[1], b, acc[1][nt]);
        }
    }
#pragma unroll
    for (int nt = 0; nt < 8; ++nt) {
        int col = nt * 16 + ln;
        float bv = bias[col];
#pragma unroll
        for (int mt = 0; mt < 2; ++mt)
#pragma unroll
            for (int r = 0; r < 4; ++r) {
                int row = rowbase + mt * 16 + q * 4 + r;
                if (row < NN) h_f16[row * HD + col] = (f16)(acc[mt][nt][r] + bv);
            }
    }
}

__global__ __launch_bounds__(256) void k_edge_lin(
    const f16* eattr, const float* ew, const float* ebias, f16* ea) {
    __shared__ float wl[16 * 128];
    __shared__ float bl[128];
    __shared__ float al[64 * 16];
    int tid = threadIdx.x;
    int eb = blockIdx.x * 64;
    for (int i = tid; i < 2048; i += 256) wl[i] = ew[i];
    if (tid < 128) bl[tid] = ebias[tid];
    {
        int e_l = tid >> 2, k0 = (tid & 3) * 4;
        int e = min(eb + e_l, NE - 1);
        f16x4 u = *(const f16x4*)(eattr + e * 16 + k0);
        al[e_l * 16 + k0 + 0] = (float)u[0];
        al[e_l * 16 + k0 + 1] = (float)u[1];
        al[e_l * 16 + k0 + 2] = (float)u[2];
        al[e_l * 16 + k0 + 3] = (float)u[3];
    }
    __syncthreads();
    for (int i = 0; i < 32; ++i) {
        int o = i * 256 + tid;
        int e_l = o >> 7, c = o & 127;
        float s = bl[c];
#pragma unroll
        for (int k = 0; k < 16; ++k) s += al[e_l * 16 + k] * wl[k * 128 + c];
        int e = eb + e_l;
        if (e < NE) ea[(size_t)e * HD + c] = (f16)s;
    }
}

// ---------------------------------------------------------------------------
// t_node = relu((h + agg) @ conv_w1 + b1)   (agg now f16)
// ---------------------------------------------------------------------------
__global__ __launch_bounds__(256) void k_conv1(
    const f16* h16, const f16* agg16, const f16* wT, const float* bias,
    f16* t_node) {
    __shared__ __align__(16) f16 wlds[16384];
    int tid = threadIdx.x;
    {
        const uint4* s = (const uint4*)wT;
        uint4* d = (uint4*)wlds;
        for (int i = tid; i < 2048; i += 256) d[i] = s[i];
    }
    __syncthreads();
    int wave = tid >> 6, lane = tid & 63, q = lane >> 4, ln = lane & 15;
    int rowbase = blockIdx.x * 128 + wave * 32;
    f32x4 acc[2][8] = {};
    for (int kt = 0; kt < 4; ++kt) {
        int koff = kt * 32 + q * 8;
        f16x8 a[2];
#pragma unroll
        for (int mt = 0; mt < 2; ++mt) {
            int row = min(rowbase + mt * 16 + ln, NN - 1);
            f16x8 hv = *(const f16x8*)(h16 + row * HD + koff);
            f16x8 gv = *(const f16x8*)(agg16 + row * HD + koff);
            f16x8 av;
#pragma unroll
            for (int j = 0; j < 8; ++j) av[j] = (f16)((float)hv[j] + (float)gv[j]);
            a[mt] = av;
        }
#pragma unroll
        for (int nt = 0; nt < 8; ++nt) {
            f16x8 b = *(const f16x8*)&wlds[(nt * 4 + kt) * 512 + lane * 8];
            acc[0][nt] = MFMA16(a[0], b, acc[0][nt]);
            acc[1][nt] = MFMA16(a[1], b, acc[1][nt]);
        }
    }
#pragma unroll
    for (int nt = 0; nt < 8; ++nt) {
        int col = nt * 16 + ln;
        float bv = bias[col];
#pragma unroll
        for (int mt = 0; mt < 2; ++mt)
#pragma unroll
            for (int r = 0; r < 4; ++r) {
                int row = rowbase + mt * 16 + q * 4 + r;
                if (row < NN)
                    t_node[row * HD + col] = (f16)fmaxf(acc[mt][nt][r] + bv, 0.f);
            }
    }
}

__global__ __launch_bounds__(256) void k_conv2(
    const f16* t_node, const f16* wT, const float* bias, f16* z2, float* stats) {
    __shared__ __align__(16) f16 wlds[16384];
    int tid = threadIdx.x;
    {
        const uint4* s = (const uint4*)wT;
        uint4* d = (uint4*)wlds;
        for (int i = tid; i < 2048; i += 256) d[i] = s[i];
    }
    __syncthreads();
    int wave = tid >> 6, lane = tid & 63, q = lane >> 4, ln = lane & 15;
    int rowbase = blockIdx.x * 128 + wave * 32;
    f32x4 acc[2][8] = {};
    for (int kt = 0; kt < 4; ++kt) {
        int koff = kt * 32 + q * 8;
        f16x8 a[2];
#pragma unroll
        for (int mt = 0; mt < 2; ++mt) {
            int row = min(rowbase + mt * 16 + ln, NN - 1);
            a[mt] = *(const f16x8*)(t_node + row * HD + koff);
        }
#pragma unroll
        for (int nt = 0; nt < 8; ++nt) {
            f16x8 b = *(const f16x8*)&wlds[(nt * 4 + kt) * 512 + lane * 8];
            acc[0][nt] = MFMA16(a[0], b, acc[0][nt]);
            acc[1][nt] = MFMA16(a[1], b, acc[1][nt]);
        }
    }
#pragma unroll
    for (int nt = 0; nt < 8; ++nt) {
        int col = nt * 16 + ln;
        float bv = bias[col];
        float s = 0.f, s2 = 0.f;
#pragma unroll
        for (int mt = 0; mt < 2; ++mt)
#pragma unroll
            for (int r = 0; r < 4; ++r) {
                int row = rowbase + mt * 16 + q * 4 + r;
                if (row < NN) {
                    float v = acc[mt][nt][r] + bv;
                    z2[row * HD + col] = (f16)v;
                    s += v;
                    s2 += v * v;
                }
            }
        s += __shfl_xor(s, 16);  s += __shfl_xor(s, 32);
        s2 += __shfl_xor(s2, 16); s2 += __shfl_xor(s2, 32);
        if (lane < 16) {
            atomicAdd(&stats[col], s);
            atomicAdd(&stats[HD + col], s2);
        }
    }
}

__global__ __launch_bounds__(256) void k_bn(
    const f16* z2, const float* stats, const float* gamma, const float* beta,
    f16* h16) {
    int gid = blockIdx.x * 256 + threadIdx.x;
    if (gid >= NN * HD / 4) return;
    int base = gid * 4;
    int c0 = base & (HD - 1);
    f16x4 z = *(const f16x4*)(z2 + base);
    f16x4 h = *(const f16x4*)(h16 + base);
    f16x4 ho;
#pragma unroll
    for (int j = 0; j < 4; ++j) {
        int c = c0 + j;
        float mu = stats[c] * (1.0f / NN);
        float var = stats[HD + c] * (1.0f / NN) - mu * mu;
        float zn = gamma[c] * ((float)z[j] - mu) * rsqrtf(var + 1e-5f) + beta[c];
        ho[j] = (f16)(((float)h[j] + fmaxf(zn, 0.f)) * 0.5f);
    }
    *(f16x4*)(h16 + base) = ho;
}

// ---------------------------------------------------------------------------
// Fused edge MLP: ea += 0.5*(relu([h_src|h_dst|ea]@W1+b1)@W2+b2).
// ---------------------------------------------------------------------------
__global__ __launch_bounds__(256) void k_emlp(
    const f16* h16, const int* eidx, const f16* w1T, const float* b1,
    const f16* w2T, const float* b2, f16* ea) {
    __shared__ __align__(16) f16 wlds[16384];
    __shared__ __align__(16) f16 t16[128 * TSTR];
    __shared__ int sidx[128], didx[128];
    int tid = threadIdx.x;
    int eb = blockIdx.x * 128;
    if (tid < 128) {
        int e = min(eb + tid, NE - 1);
        sidx[tid] = eidx[e];
        didx[tid] = eidx[NE + e];
    }
    int wave = tid >> 6, lane = tid & 63, q = lane >> 4, ln = lane & 15;
    f32x4 acc[2][8] = {};
    for (int seg = 0; seg < 3; ++seg) {
        __syncthreads();
        {
            const uint4* s = (const uint4*)(w1T + seg * 16384);
            uint4* d = (uint4*)wlds;
            for (int i = tid; i < 2048; i += 256) d[i] = s[i];
        }
        __syncthreads();
        for (int kt = 0; kt < 4; ++kt) {
            int koff = kt * 32 + q * 8;
            f16x8 a[2];
#pragma unroll
            for (int mt = 0; mt < 2; ++mt) {
                int le = wave * 32 + mt * 16 + ln;
                const f16* ap;
                if (seg == 0)      ap = h16 + (size_t)sidx[le] * HD + koff;
                else if (seg == 1) ap = h16 + (size_t)didx[le] * HD + koff;
                else               ap = ea + (size_t)min(eb + le, NE - 1) * HD + koff;
                a[mt] = *(const f16x8*)ap;
            }
#pragma unroll
            for (int nt = 0; nt < 8; ++nt) {
                f16x8 b = *(const f16x8*)&wlds[(nt * 4 + kt) * 512 + lane * 8];
                acc[0][nt] = MFMA16(a[0], b, acc[0][nt]);
                acc[1][nt] = MFMA16(a[1], b, acc[1][nt]);
            }
        }
    }
#pragma unroll
    for (int nt = 0; nt < 8; ++nt) {
        int col = nt * 16 + ln;
        float bv = b1[col];
#pragma unroll
        for (int mt = 0; mt < 2; ++mt)
#pragma unroll
            for (int r = 0; r < 4; ++r) {
                int row = wave * 32 + mt * 16 + q * 4 + r;
                t16[row * TSTR + col] = (f16)fmaxf(acc[mt][nt][r] + bv, 0.f);
            }
    }
    __syncthreads();
    {
        const uint4* s = (const uint4*)w2T;
        uint4* d = (uint4*)wlds;
        for (int i = tid; i < 2048; i += 256) d[i] = s[i];
    }
    __syncthreads();
    f32x4 acc2[2][8] = {};
    for (int kt = 0; kt < 4; ++kt) {
        int koff = kt * 32 + q * 8;
        f16x8 a[2];
#pragma unroll
        for (int mt = 0; mt < 2; ++mt) {
            int le = wave * 32 + mt * 16 + ln;
            a[mt] = *(const f16x8*)&t16[le * TSTR + koff];
        }
#pragma unroll
        for (int nt = 0; nt < 8; ++nt) {
            f16x8 b = *(const f16x8*)&wlds[(nt * 4 + kt) * 512 + lane * 8];
            acc2[0][nt] = MFMA16(a[0], b, acc2[0][nt]);
            acc2[1][nt] = MFMA16(a[1], b, acc2[1][nt]);
        }
    }
#pragma unroll
    for (int nt = 0; nt < 8; ++nt) {
        int col = nt * 16 + ln;
        float bv = b2[col];
#pragma unroll
        for (int mt = 0; mt < 2; ++mt)
#pragma unroll
            for (int r = 0; r < 4; ++r) {
                int e = eb + wave * 32 + mt * 16 + q * 4 + r;
                if (e < NE) {
                    size_t o = (size_t)e * HD + col;
                    ea[o] = (f16)((float)ea[o] + 0.5f * (acc2[mt][nt][r] + bv));
                }
            }
    }
}

// ---------------------------------------------------------------------------
__global__ __launch_bounds__(256) void k_readout(
    const f16* h16, const f16* ea, const int* eidx, const f16* w1Tp,
    const float* mb1, const float* mw2, const float* mb2,
    const float* mw3, const float* mb3, float* out) {
    __shared__ __align__(16) f16 wlds[8192];
    __shared__ f16 o1[256 * 58];
    __shared__ float w2l[50 * 28];
    __shared__ float w3l[50];
    __shared__ float b2l[25];
    __shared__ float b3l[2];
    __shared__ int sidx[256], didx[256];
    int tid = threadIdx.x;
    int eb = blockIdx.x * 256;
    {
        int e = min(eb + tid, NE - 1);
        sidx[tid] = eidx[e];
        didx[tid] = eidx[NE + e];
    }
    for (int i = tid; i < 50 * 28; i += 256) {
        int k = i / 28, ko = i - k * 28;
        w2l[i] = (ko < 25) ? mw2[k * 25 + ko] : 0.f;
    }
    if (tid < 50) w3l[tid] = mw3[tid];
    if (tid < 25) b2l[tid] = mb2[tid];
    if (tid < 2) b3l[tid] = mb3[tid];
    int wave = tid >> 6, lane = tid & 63, q = lane >> 4, ln = lane & 15;
    f32x4 acc[4][4] = {};
    for (int seg = 0; seg < 3; ++seg) {
        __syncthreads();
        {
            const uint4* s = (const uint4*)(w1Tp + seg * 8192);
            uint4* d = (uint4*)wlds;
            for (int i = tid; i < 1024; i += 256) d[i] = s[i];
        }
        __syncthreads();
        for (int kt = 0; kt < 4; ++kt) {
            int koff = kt * 32 + q * 8;
            f16x8 a[4];
#pragma unroll
            for (int mt = 0; mt < 4; ++mt) {
                int le = wave * 64 + mt * 16 + ln;
                const f16* ap;
                if (seg == 0)      ap = h16 + (size_t)sidx[le] * HD + koff;
                else if (seg == 1) ap = h16 + (size_t)didx[le] * HD + koff;
                else               ap = ea + (size_t)min(eb + le, NE - 1) * HD + koff;
                a[mt] = *(const f16x8*)ap;
            }
#pragma unroll
            for (int nt = 0; nt < 4; ++nt) {
                f16x8 b = *(const f16x8*)&wlds[(nt * 4 + kt) * 512 + lane * 8];
#pragma unroll
                for (int mt = 0; mt < 4; ++mt)
                    acc[mt][nt] = MFMA16(a[mt], b, acc[mt][nt]);
            }
        }
    }
#pragma unroll
    for (int nt = 0; nt < 4; ++nt) {
        int col = nt * 16 + ln;
        if (col < 50) {
            float bv = mb1[col];
#pragma unroll
            for (int mt = 0; mt < 4; ++mt)
#pragma unroll
                for (int r = 0; r < 4; ++r) {
                    int le = wave * 64 + mt * 16 + q * 4 + r;
                    o1[le * 58 + col] = (f16)fmaxf(acc[mt][nt][r] + bv, 0.f);
                }
        }
    }
    __syncthreads();
    float o2[25];
#pragma unroll
    for (int ko = 0; ko < 25; ++ko) o2[ko] = b2l[ko];
    for (int k = 0; k < 50; ++k) {
        float a = (float)o1[tid * 58 + k];
#pragma unroll
        for (int ko = 0; ko < 25; ++ko) o2[ko] += a * w2l[k * 28 + ko];
    }
    float r0 = b3l[0], r1 = b3l[1];
#pragma unroll
    for (int ko = 0; ko < 25; ++ko) {
        float a = fmaxf(o2[ko], 0.f);
        r0 += a * w3l[ko * 2];
        r1 += a * w3l[ko * 2 + 1];
    }
    int e = eb + tid;
    if (e < NE) {
        float2 o; o.x = r0; o.y = r1;
        *(float2*)(out + (size_t)e * 2) = o;
    }
}

// ---------------------------------------------------------------------------
extern "C" void kernel_launch(void* const* d_in, const int* in_sizes, int n_in,
                              void* d_out, int out_size, void* d_ws, size_t ws_size,
                              hipStream_t stream) {
    // ws layout (bytes):
    //   ea      : 0            .. 128,000,000  (f16 E*128)
    //   hf16    : 128,000,000  .. 140,800,000  (f16 N*128)
    //   agg16   : 140,800,000  .. 153,600,000  (f16 N*128) [alias: eattr16 16MB
    //             spans 140.8M..156.8M — dead after k_edge_lin]
    //   eord    : 153,600,000  .. 155,600,000  (i32 E)
    //   off     : 155,600,000  .. 155,800,064  (i32 NN+1)
    //   cntcur  : 155,800,064  .. 156,000,064  (i32 NN)  [cnt then cursor]
    //   bsum    : 156,000,064  .. 156,001,088  (i32 196)
    //   bpre    : 156,001,088  .. 156,002,112  (i32 196)
    //   z2      : 166,400,000  .. 179,200,000  (f16 N*128) [alias: xc]
    //   tn      : 179,200,000  .. 192,000,000  (f16 N*128)
    //   wbuf    : 192,000,000  .. 192,475,136
    //   stats   : 192,475,136  .. 192,476,160
    //   prm     : 192,476,160  .. 193,425,796
    //   eix     : 193,425,920  .. 197,425,920  (i32 2E)
    //   flags   : 197,425,920  .. 197,425,936
    const size_t WS_NEED = 197425936ULL;
    if (ws_size < WS_NEED) {
        hipMemsetAsync(d_out, 0, (size_t)out_size * 4, stream);
        return;
    }
    char* ws = (char*)d_ws;
    f16* ea = (f16*)(ws);
    f16* hf16 = (f16*)(ws + 128000000LL);
    f16* agg16 = (f16*)(ws + 140800000LL);
    f16* eattr16 = (f16*)(ws + 140800000LL);
    int* eord = (int*)(ws + 153600000LL);
    int* off = (int*)(ws + 155600000LL);
    int* cntcur = (int*)(ws + 155800064LL);
    int* bsum = (int*)(ws + 156000064LL);
    int* bpre = (int*)(ws + 156001088LL);
    f16* z2 = (f16*)(ws + 166400000LL);
    f16* xc = (f16*)(ws + 166400000LL);
    f16* tn = (f16*)(ws + 179200000LL);
    f16* wbuf = (f16*)(ws + 192000000LL);
    float* stats = (float*)(ws + 192475136LL);
    float* prm = (float*)(ws + 192476160LL);
    int* eix = (int*)(ws + 193425920LL);
    int* flags = (int*)(ws + 197425920LL);
    float* out = (float*)d_out;

    k_detect<<<1, 256, 0, stream>>>((const unsigned int*)d_in[2],
                                    (const int*)d_in[22], flags);
    k_cvt<<<6250, 256, 0, stream>>>(d_in[0], xc, 1600000, flags);
    k_cvt<<<7813, 256, 0, stream>>>(d_in[1], eattr16, 2000000, flags);
    k_cvt_prm<<<928, 256, 0, stream>>>(
        d_in[2], d_in[3], d_in[4], d_in[5], d_in[6], d_in[7], d_in[8], d_in[9],
        d_in[10], d_in[11], d_in[12], d_in[13], d_in[14], d_in[15], d_in[16],
        d_in[17], d_in[18], d_in[19], d_in[20], d_in[21], prm, flags);
    k_cvt_idx<<<3907, 256, 0, stream>>>((const int*)d_in[22], eix, flags);

    k_prep<<<928, 256, 0, stream>>>(prm, wbuf);
    k_node_lin<<<391, 256, 0, stream>>>(xc, wbuf, prm + P_NODE_B, hf16);
    k_edge_lin<<<7813, 256, 0, stream>>>(eattr16, prm + P_EDGE_W, prm + P_EDGE_B, ea);
    // eattr16 dead from here; CSR arrays may overwrite its tail.

    hipMemsetAsync(cntcur, 0, NN * 4, stream);
    k_hist<<<1954, 256, 0, stream>>>(eix, cntcur);
    k_scanA<<<196, 256, 0, stream>>>(cntcur, bsum);
    k_scanB<<<1, 256, 0, stream>>>(bsum, bpre, off);
    k_scanC<<<196, 256, 0, stream>>>(cntcur, bpre, off, cntcur);
    k_scatter<<<1954, 256, 0, stream>>>(eix, cntcur, eord);

    for (int l = 0; l < 2; ++l) {
        hipMemsetAsync(stats, 0, 1024, stream);
        k_agg<<<12500, 256, 0, stream>>>(ea, hf16, eix, off, eord, agg16);
        k_conv1<<<391, 256, 0, stream>>>(hf16, agg16, wbuf + (1 + l) * 16384,
                                         prm + P_CONV_B1 + l * HD, tn);
        k_conv2<<<391, 256, 0, stream>>>(tn, wbuf + (3 + l) * 16384,
                                         prm + P_CONV_B2 + l * HD, z2, stats);
        k_bn<<<6250, 256, 0, stream>>>(z2, stats, prm + P_GAMMA + l * HD,
                                       prm + P_BETA + l * HD, hf16);
        k_emlp<<<3907, 256, 0, stream>>>(hf16, eix, wbuf + (5 + l * 3) * 16384,
                                         prm + P_EMLP_B1 + l * HD,
                                         wbuf + (11 + l) * 16384,
                                         prm + P_EMLP_B2 + l * HD, ea);
    }
    k_readout<<<1954, 256, 0, stream>>>(hf16, ea, eix, wbuf + 13 * 16384,
                                        prm + P_MLP_B1, prm + P_MLP_W2,
                                        prm + P_MLP_B2, prm + P_MLP_W3,
                                        prm + P_MLP_B3, out);
}

// Round 6
// 1102.872 us; speedup vs baseline: 1.5770x; 1.0157x over previous
//
#include <hip/hip_runtime.h>

// GINe forward: N=50000 nodes, E=500000 edges, H=128, L=2 layers, C=2.
// fp32 inputs, int32 edge_index, fp32 output [E,2] (confirmed round 4).
// R6: k_emlp was latency-bound (Occ 20.5%, 72.7KB LDS -> 2 blk/CU, serialized
// gathers). Now 64-edge blocks (52.3KB -> 3 blk/CU) + hoisted unrolled gathers.

#define NN 50000
#define NE 500000
#define HD 128

typedef _Float16 f16;
typedef _Float16 f16x8 __attribute__((ext_vector_type(8)));
typedef _Float16 f16x4 __attribute__((ext_vector_type(4)));
typedef _Float16 f16x2 __attribute__((ext_vector_type(2)));
typedef float f32x4 __attribute__((ext_vector_type(4)));
typedef unsigned short ushort_t;

#define MFMA16(a, b, c) __builtin_amdgcn_mfma_f32_16x16x32_f16((a), (b), (c), 0, 0, 0)

#define TSTR 152

// f32 param blob offsets (element units)
#define P_NODE_W 0
#define P_NODE_B 16384
#define P_EDGE_W 16512
#define P_EDGE_B 18560
#define P_CONV_W1 18688
#define P_CONV_B1 51456
#define P_CONV_W2 51712
#define P_CONV_B2 84480
#define P_GAMMA 84736
#define P_BETA 84992
#define P_EMLP_W1 85248
#define P_EMLP_B1 183552
#define P_EMLP_W2 183808
#define P_EMLP_B2 216576
#define P_MLP_W1 216832
#define P_MLP_B1 236032
#define P_MLP_W2 236082
#define P_MLP_B2 237332
#define P_MLP_W3 237357
#define P_MLP_B3 237407
#define P_TOTAL 237409

__device__ __forceinline__ float bf2f(unsigned short u) {
    union { unsigned int i; float f; } v;
    v.i = ((unsigned int)u) << 16;
    return v.f;
}

// ---------------------------------------------------------------------------
__global__ __launch_bounds__(256) void k_detect(
    const unsigned int* nw, const int* ei, int* flags) {
    __shared__ int cF, cI;
    if (threadIdx.x == 0) { cF = 0; cI = 0; }
    __syncthreads();
    unsigned int u = nw[threadIdx.x];
    int e = (int)((u >> 7) & 0xFFu);
    int odd = ei[2 * threadIdx.x + 1];
    if (e >= 100 && e <= 140) atomicAdd(&cF, 1);
    if (odd != 0) atomicAdd(&cI, 1);
    __syncthreads();
    if (threadIdx.x == 0) {
        flags[0] = (cF < 160) ? 1 : 0;
        flags[1] = (cI < 64) ? 1 : 0;
    }
}

__global__ __launch_bounds__(256) void k_cvt(
    const void* src, f16* dst, int n4, const int* flags) {
    int i = blockIdx.x * 256 + threadIdx.x;
    if (i >= n4) return;
    f16x4 o;
    if (flags[0]) {
        float4 v = ((const float4*)src)[i];
        o[0] = (f16)v.x; o[1] = (f16)v.y; o[2] = (f16)v.z; o[3] = (f16)v.w;
    } else {
        ushort4 v = ((const ushort4*)src)[i];
        o[0] = (f16)bf2f(v.x); o[1] = (f16)bf2f(v.y);
        o[2] = (f16)bf2f(v.z); o[3] = (f16)bf2f(v.w);
    }
    ((f16x4*)dst)[i] = o;
}

__global__ __launch_bounds__(256) void k_cvt_prm(
    const void* p0, const void* p1, const void* p2, const void* p3,
    const void* p4, const void* p5, const void* p6, const void* p7,
    const void* p8, const void* p9, const void* p10, const void* p11,
    const void* p12, const void* p13, const void* p14, const void* p15,
    const void* p16, const void* p17, const void* p18, const void* p19,
    float* prm, const int* flags) {
    int i = blockIdx.x * 256 + threadIdx.x;
    if (i >= P_TOTAL) return;
    const int offs[21] = {P_NODE_W, P_NODE_B, P_EDGE_W, P_EDGE_B, P_CONV_W1,
                          P_CONV_B1, P_CONV_W2, P_CONV_B2, P_GAMMA, P_BETA,
                          P_EMLP_W1, P_EMLP_B1, P_EMLP_W2, P_EMLP_B2, P_MLP_W1,
                          P_MLP_B1, P_MLP_W2, P_MLP_B2, P_MLP_W3, P_MLP_B3,
                          P_TOTAL};
    const void* srcs[20] = {p0, p1, p2, p3, p4, p5, p6, p7, p8, p9, p10, p11,
                            p12, p13, p14, p15, p16, p17, p18, p19};
    int s = 0;
#pragma unroll
    for (int k = 1; k < 20; ++k)
        if (i >= offs[k]) s = k;
    int li = i - offs[s];
    float v = flags[0] ? ((const float*)srcs[s])[li]
                       : bf2f(((const ushort_t*)srcs[s])[li]);
    prm[i] = v;
}

__global__ __launch_bounds__(256) void k_cvt_idx(
    const int* src, int* dst, const int* flags) {
    int i = blockIdx.x * 256 + threadIdx.x;
    if (i >= 2 * NE) return;
    dst[i] = flags[1] ? src[2 * i] : src[i];
}

// ---------------------------------------------------------------------------
// CSR build: hist -> 3-phase exclusive scan -> scatter permutation.
// ---------------------------------------------------------------------------
__global__ __launch_bounds__(256) void k_hist(const int* eix, int* cnt) {
    int e = blockIdx.x * 256 + threadIdx.x;
    if (e < NE) atomicAdd(&cnt[eix[NE + e]], 1);
}

__global__ __launch_bounds__(256) void k_scanA(const int* cnt, int* bsum) {
    __shared__ int wsum[4];
    int tid = threadIdx.x;
    int i = blockIdx.x * 256 + tid;
    int v = (i < NN) ? cnt[i] : 0;
#pragma unroll
    for (int s = 1; s < 64; s <<= 1) v += __shfl_xor(v, s);
    if ((tid & 63) == 0) wsum[tid >> 6] = v;
    __syncthreads();
    if (tid == 0) bsum[blockIdx.x] = wsum[0] + wsum[1] + wsum[2] + wsum[3];
}

__global__ __launch_bounds__(256) void k_scanB(const int* bsum, int* bpre, int* off) {
    __shared__ int l[200];
    int tid = threadIdx.x;
    if (tid < 196) l[tid] = bsum[tid];
    __syncthreads();
    if (tid == 0) {
        int run = 0;
        for (int b = 0; b < 196; ++b) { int t = l[b]; l[b] = run; run += t; }
        off[NN] = run;
    }
    __syncthreads();
    if (tid < 196) bpre[tid] = l[tid];
}

__global__ __launch_bounds__(256) void k_scanC(
    const int* cnt, const int* bpre, int* off, int* cursor) {
    __shared__ int wsum[4];
    int tid = threadIdx.x;
    int lane = tid & 63, wave = tid >> 6;
    int i = blockIdx.x * 256 + tid;
    int v = (i < NN) ? cnt[i] : 0;
    int incl = v;
#pragma unroll
    for (int s = 1; s < 64; s <<= 1) {
        int t = __shfl_up(incl, s);
        if (lane >= s) incl += t;
    }
    if (lane == 63) wsum[wave] = incl;
    __syncthreads();
    int add = bpre[blockIdx.x];
    for (int w = 0; w < 4; ++w)
        if (w < wave) add += wsum[w];
    int excl = add + incl - v;
    if (i < NN) { off[i] = excl; cursor[i] = excl; }
}

__global__ __launch_bounds__(256) void k_scatter(
    const int* eix, int* cursor, int* eord) {
    int e = blockIdx.x * 256 + threadIdx.x;
    if (e >= NE) return;
    int d = eix[NE + e];
    int pos = atomicAdd(&cursor[d], 1);
    eord[pos] = e;
}

// ---------------------------------------------------------------------------
// CSR gather: agg[n] = sum_{e in in(n)} relu(h[src[e]] + ea[e]).
// ---------------------------------------------------------------------------
__global__ __launch_bounds__(256) void k_agg(
    const f16* ea, const f16* h16, const int* eix, const int* off,
    const int* eord, f16* agg16) {
    int wid = (blockIdx.x * 256 + threadIdx.x) >> 6;
    int lane = threadIdx.x & 63;
    int beg = off[wid], end = off[wid + 1];
    float a0 = 0.f, a1 = 0.f;
    for (int i = beg; i < end; ++i) {
        int e = eord[i];
        int s = eix[e];
        f16x2 ev = *(const f16x2*)(ea + (size_t)e * HD + lane * 2);
        f16x2 hv = *(const f16x2*)(h16 + (size_t)s * HD + lane * 2);
        a0 += fmaxf((float)ev[0] + (float)hv[0], 0.f);
        a1 += fmaxf((float)ev[1] + (float)hv[1], 0.f);
    }
    f16x2 o; o[0] = (f16)a0; o[1] = (f16)a1;
    *(f16x2*)(agg16 + (size_t)wid * HD + lane * 2) = o;
}

// ---------------------------------------------------------------------------
// Prep: swizzle all MFMA weight matrices into B-fragment order.
// ---------------------------------------------------------------------------
__global__ __launch_bounds__(256) void k_prep(const float* prm, f16* wbuf) {
    int gid = blockIdx.x * 256 + threadIdx.x;
    if (gid < 13 * 16384) {
        int seg = gid >> 14;
        int idx = gid & 16383;
        int off;
        switch (seg) {
            case 0: off = P_NODE_W; break;
            case 1: off = P_CONV_W1; break;
            case 2: off = P_CONV_W1 + 16384; break;
            case 3: off = P_CONV_W2; break;
            case 4: off = P_CONV_W2 + 16384; break;
            case 5: case 6: case 7: off = P_EMLP_W1 + (seg - 5) * 16384; break;
            case 8: case 9: case 10: off = P_EMLP_W1 + 49152 + (seg - 8) * 16384; break;
            case 11: off = P_EMLP_W2; break;
            default: off = P_EMLP_W2 + 16384; break;
        }
        int fb = idx >> 9;
        int sub = (idx & 511) >> 3;
        int j = idx & 7;
        int q = sub >> 4, n = sub & 15;
        int nt = fb >> 2, kt = fb & 3;
        int k = kt * 32 + q * 8 + j;
        int c = nt * 16 + n;
        wbuf[gid] = (f16)prm[off + k * 128 + c];
    } else {
        int t = gid - 13 * 16384;
        if (t >= 3 * 8192) return;
        int s = t >> 13;
        int idx = t & 8191;
        int fb = idx >> 9;
        int sub = (idx & 511) >> 3;
        int j = idx & 7;
        int q = sub >> 4, n = sub & 15;
        int nt = fb >> 2, kt = fb & 3;
        int k = s * 128 + kt * 32 + q * 8 + j;
        int c = nt * 16 + n;
        float v = (c < 50) ? prm[P_MLP_W1 + k * 50 + c] : 0.f;
        wbuf[13 * 16384 + s * 8192 + idx] = (f16)v;
    }
}

// ---------------------------------------------------------------------------
__global__ __launch_bounds__(256) void k_node_lin(
    const f16* xc, const f16* wT, const float* bias, f16* h_f16) {
    __shared__ __align__(16) f16 wlds[16384];
    int tid = threadIdx.x;
    {
        const uint4* s = (const uint4*)wT;
        uint4* d = (uint4*)wlds;
        for (int i = tid; i < 2048; i += 256) d[i] = s[i];
    }
    __syncthreads();
    int wave = tid >> 6, lane = tid & 63, q = lane >> 4, ln = lane & 15;
    int rowbase = blockIdx.x * 128 + wave * 32;
    f32x4 acc[2][8] = {};
#pragma unroll
    for (int kt = 0; kt < 4; ++kt) {
        int koff = kt * 32 + q * 8;
        f16x8 a[2];
#pragma unroll
        for (int mt = 0; mt < 2; ++mt) {
            int row = min(rowbase + mt * 16 + ln, NN - 1);
            a[mt] = *(const f16x8*)(xc + row * HD + koff);
        }
#pragma unroll
        for (int nt = 0; nt < 8; ++nt) {
            f16x8 b = *(const f16x8*)&wlds[(nt * 4 + kt) * 512 + lane * 8];
            acc[0][nt] = MFMA16(a[0], b, acc[0][nt]);
            acc[1][nt] = MFMA16(a[1], b, acc[1][nt]);
        }
    }
#pragma unroll
    for (int nt = 0; nt < 8; ++nt) {
        int col = nt * 16 + ln;
        float bv = bias[col];
#pragma unroll
        for (int mt = 0; mt < 2; ++mt)
#pragma unroll
            for (int r = 0; r < 4; ++r) {
                int row = rowbase + mt * 16 + q * 4 + r;
                if (row < NN) h_f16[row * HD + col] = (f16)(acc[mt][nt][r] + bv);
            }
    }
}

__global__ __launch_bounds__(256) void k_edge_lin(
    const f16* eattr, const float* ew, const float* ebias, f16* ea) {
    __shared__ float wl[16 * 128];
    __shared__ float bl[128];
    __shared__ float al[64 * 16];
    int tid = threadIdx.x;
    int eb = blockIdx.x * 64;
    for (int i = tid; i < 2048; i += 256) wl[i] = ew[i];
    if (tid < 128) bl[tid] = ebias[tid];
    {
        int e_l = tid >> 2, k0 = (tid & 3) * 4;
        int e = min(eb + e_l, NE - 1);
        f16x4 u = *(const f16x4*)(eattr + e * 16 + k0);
        al[e_l * 16 + k0 + 0] = (float)u[0];
        al[e_l * 16 + k0 + 1] = (float)u[1];
        al[e_l * 16 + k0 + 2] = (float)u[2];
        al[e_l * 16 + k0 + 3] = (float)u[3];
    }
    __syncthreads();
    for (int i = 0; i < 32; ++i) {
        int o = i * 256 + tid;
        int e_l = o >> 7, c = o & 127;
        float s = bl[c];
#pragma unroll
        for (int k = 0; k < 16; ++k) s += al[e_l * 16 + k] * wl[k * 128 + c];
        int e = eb + e_l;
        if (e < NE) ea[(size_t)e * HD + c] = (f16)s;
    }
}

// ---------------------------------------------------------------------------
// t_node = relu((h + agg) @ conv_w1 + b1)
// ---------------------------------------------------------------------------
__global__ __launch_bounds__(256) void k_conv1(
    const f16* h16, const f16* agg16, const f16* wT, const float* bias,
    f16* t_node) {
    __shared__ __align__(16) f16 wlds[16384];
    int tid = threadIdx.x;
    {
        const uint4* s = (const uint4*)wT;
        uint4* d = (uint4*)wlds;
        for (int i = tid; i < 2048; i += 256) d[i] = s[i];
    }
    __syncthreads();
    int wave = tid >> 6, lane = tid & 63, q = lane >> 4, ln = lane & 15;
    int rowbase = blockIdx.x * 128 + wave * 32;
    f32x4 acc[2][8] = {};
#pragma unroll
    for (int kt = 0; kt < 4; ++kt) {
        int koff = kt * 32 + q * 8;
        f16x8 a[2];
#pragma unroll
        for (int mt = 0; mt < 2; ++mt) {
            int row = min(rowbase + mt * 16 + ln, NN - 1);
            f16x8 hv = *(const f16x8*)(h16 + row * HD + koff);
            f16x8 gv = *(const f16x8*)(agg16 + row * HD + koff);
            f16x8 av;
#pragma unroll
            for (int j = 0; j < 8; ++j) av[j] = (f16)((float)hv[j] + (float)gv[j]);
            a[mt] = av;
        }
#pragma unroll
        for (int nt = 0; nt < 8; ++nt) {
            f16x8 b = *(const f16x8*)&wlds[(nt * 4 + kt) * 512 + lane * 8];
            acc[0][nt] = MFMA16(a[0], b, acc[0][nt]);
            acc[1][nt] = MFMA16(a[1], b, acc[1][nt]);
        }
    }
#pragma unroll
    for (int nt = 0; nt < 8; ++nt) {
        int col = nt * 16 + ln;
        float bv = bias[col];
#pragma unroll
        for (int mt = 0; mt < 2; ++mt)
#pragma unroll
            for (int r = 0; r < 4; ++r) {
                int row = rowbase + mt * 16 + q * 4 + r;
                if (row < NN)
                    t_node[row * HD + col] = (f16)fmaxf(acc[mt][nt][r] + bv, 0.f);
            }
    }
}

__global__ __launch_bounds__(256) void k_conv2(
    const f16* t_node, const f16* wT, const float* bias, f16* z2, float* stats) {
    __shared__ __align__(16) f16 wlds[16384];
    int tid = threadIdx.x;
    {
        const uint4* s = (const uint4*)wT;
        uint4* d = (uint4*)wlds;
        for (int i = tid; i < 2048; i += 256) d[i] = s[i];
    }
    __syncthreads();
    int wave = tid >> 6, lane = tid & 63, q = lane >> 4, ln = lane & 15;
    int rowbase = blockIdx.x * 128 + wave * 32;
    f32x4 acc[2][8] = {};
#pragma unroll
    for (int kt = 0; kt < 4; ++kt) {
        int koff = kt * 32 + q * 8;
        f16x8 a[2];
#pragma unroll
        for (int mt = 0; mt < 2; ++mt) {
            int row = min(rowbase + mt * 16 + ln, NN - 1);
            a[mt] = *(const f16x8*)(t_node + row * HD + koff);
        }
#pragma unroll
        for (int nt = 0; nt < 8; ++nt) {
            f16x8 b = *(const f16x8*)&wlds[(nt * 4 + kt) * 512 + lane * 8];
            acc[0][nt] = MFMA16(a[0], b, acc[0][nt]);
            acc[1][nt] = MFMA16(a[1], b, acc[1][nt]);
        }
    }
#pragma unroll
    for (int nt = 0; nt < 8; ++nt) {
        int col = nt * 16 + ln;
        float bv = bias[col];
        float s = 0.f, s2 = 0.f;
#pragma unroll
        for (int mt = 0; mt < 2; ++mt)
#pragma unroll
            for (int r = 0; r < 4; ++r) {
                int row = rowbase + mt * 16 + q * 4 + r;
                if (row < NN) {
                    float v = acc[mt][nt][r] + bv;
                    z2[row * HD + col] = (f16)v;
                    s += v;
                    s2 += v * v;
                }
            }
        s += __shfl_xor(s, 16);  s += __shfl_xor(s, 32);
        s2 += __shfl_xor(s2, 16); s2 += __shfl_xor(s2, 32);
        if (lane < 16) {
            atomicAdd(&stats[col], s);
            atomicAdd(&stats[HD + col], s2);
        }
    }
}

__global__ __launch_bounds__(256) void k_bn(
    const f16* z2, const float* stats, const float* gamma, const float* beta,
    f16* h16) {
    int gid = blockIdx.x * 256 + threadIdx.x;
    if (gid >= NN * HD / 4) return;
    int base = gid * 4;
    int c0 = base & (HD - 1);
    f16x4 z = *(const f16x4*)(z2 + base);
    f16x4 h = *(const f16x4*)(h16 + base);
    f16x4 ho;
#pragma unroll
    for (int j = 0; j < 4; ++j) {
        int c = c0 + j;
        float mu = stats[c] * (1.0f / NN);
        float var = stats[HD + c] * (1.0f / NN) - mu * mu;
        float zn = gamma[c] * ((float)z[j] - mu) * rsqrtf(var + 1e-5f) + beta[c];
        ho[j] = (f16)(((float)h[j] + fmaxf(zn, 0.f)) * 0.5f);
    }
    *(f16x4*)(h16 + base) = ho;
}

// ---------------------------------------------------------------------------
// Fused edge MLP: ea += 0.5*(relu([h_src|h_dst|ea]@W1+b1)@W2+b2).
// R6: 64-edge blocks (LDS 52.3KB -> 3 blk/CU), gathers hoisted+unrolled.
// Wave: 16 edges x 128 cols, acc[8].
// ---------------------------------------------------------------------------
__global__ __launch_bounds__(256) void k_emlp(
    const f16* h16, const int* eidx, const f16* w1T, const float* b1,
    const f16* w2T, const float* b2, f16* ea) {
    __shared__ __align__(16) f16 wlds[16384];
    __shared__ __align__(16) f16 t16[64 * TSTR];
    __shared__ int sidx[64], didx[64];
    int tid = threadIdx.x;
    int eb = blockIdx.x * 64;
    if (tid < 64) {
        int e = min(eb + tid, NE - 1);
        sidx[tid] = eidx[e];
        didx[tid] = eidx[NE + e];
    }
    int wave = tid >> 6, lane = tid & 63, q = lane >> 4, ln = lane & 15;
    int le = wave * 16 + ln;
    f32x4 acc[8] = {};
    for (int seg = 0; seg < 3; ++seg) {
        __syncthreads();
        {
            const uint4* s = (const uint4*)(w1T + seg * 16384);
            uint4* d = (uint4*)wlds;
            for (int i = tid; i < 2048; i += 256) d[i] = s[i];
        }
        __syncthreads();
        const f16* base;
        if (seg == 0)      base = h16 + (size_t)sidx[le] * HD;
        else if (seg == 1) base = h16 + (size_t)didx[le] * HD;
        else               base = ea + (size_t)min(eb + le, NE - 1) * HD;
        f16x8 a[4];
#pragma unroll
        for (int kt = 0; kt < 4; ++kt)
            a[kt] = *(const f16x8*)(base + kt * 32 + q * 8);
#pragma unroll
        for (int kt = 0; kt < 4; ++kt)
#pragma unroll
            for (int nt = 0; nt < 8; ++nt) {
                f16x8 b = *(const f16x8*)&wlds[(nt * 4 + kt) * 512 + lane * 8];
                acc[nt] = MFMA16(a[kt], b, acc[nt]);
            }
    }
    // t = relu(acc + b1) -> LDS tile
#pragma unroll
    for (int nt = 0; nt < 8; ++nt) {
        int col = nt * 16 + ln;
        float bv = b1[col];
#pragma unroll
        for (int r = 0; r < 4; ++r) {
            int row = wave * 16 + q * 4 + r;
            t16[row * TSTR + col] = (f16)fmaxf(acc[nt][r] + bv, 0.f);
        }
    }
    __syncthreads();
    {
        const uint4* s = (const uint4*)w2T;
        uint4* d = (uint4*)wlds;
        for (int i = tid; i < 2048; i += 256) d[i] = s[i];
    }
    __syncthreads();
    f32x4 acc2[8] = {};
    {
        f16x8 a2[4];
#pragma unroll
        for (int kt = 0; kt < 4; ++kt)
            a2[kt] = *(const f16x8*)&t16[le * TSTR + kt * 32 + q * 8];
#pragma unroll
        for (int kt = 0; kt < 4; ++kt)
#pragma unroll
            for (int nt = 0; nt < 8; ++nt) {
                f16x8 b = *(const f16x8*)&wlds[(nt * 4 + kt) * 512 + lane * 8];
                acc2[nt] = MFMA16(a2[kt], b, acc2[nt]);
            }
    }
#pragma unroll
    for (int nt = 0; nt < 8; ++nt) {
        int col = nt * 16 + ln;
        float bv = b2[col];
#pragma unroll
        for (int r = 0; r < 4; ++r) {
            int e = eb + wave * 16 + q * 4 + r;
            if (e < NE) {
                size_t o = (size_t)e * HD + col;
                ea[o] = (f16)((float)ea[o] + 0.5f * (acc2[nt][r] + bv));
            }
        }
    }
}

// ---------------------------------------------------------------------------
__global__ __launch_bounds__(256) void k_readout(
    const f16* h16, const f16* ea, const int* eidx, const f16* w1Tp,
    const float* mb1, const float* mw2, const float* mb2,
    const float* mw3, const float* mb3, float* out) {
    __shared__ __align__(16) f16 wlds[8192];
    __shared__ f16 o1[256 * 58];
    __shared__ float w2l[50 * 28];
    __shared__ float w3l[50];
    __shared__ float b2l[25];
    __shared__ float b3l[2];
    __shared__ int sidx[256], didx[256];
    int tid = threadIdx.x;
    int eb = blockIdx.x * 256;
    {
        int e = min(eb + tid, NE - 1);
        sidx[tid] = eidx[e];
        didx[tid] = eidx[NE + e];
    }
    for (int i = tid; i < 50 * 28; i += 256) {
        int k = i / 28, ko = i - k * 28;
        w2l[i] = (ko < 25) ? mw2[k * 25 + ko] : 0.f;
    }
    if (tid < 50) w3l[tid] = mw3[tid];
    if (tid < 25) b2l[tid] = mb2[tid];
    if (tid < 2) b3l[tid] = mb3[tid];
    int wave = tid >> 6, lane = tid & 63, q = lane >> 4, ln = lane & 15;
    f32x4 acc[4][4] = {};
    for (int seg = 0; seg < 3; ++seg) {
        __syncthreads();
        {
            const uint4* s = (const uint4*)(w1Tp + seg * 8192);
            uint4* d = (uint4*)wlds;
            for (int i = tid; i < 1024; i += 256) d[i] = s[i];
        }
        __syncthreads();
#pragma unroll
        for (int kt = 0; kt < 4; ++kt) {
            int koff = kt * 32 + q * 8;
            f16x8 a[4];
#pragma unroll
            for (int mt = 0; mt < 4; ++mt) {
                int le = wave * 64 + mt * 16 + ln;
                const f16* ap;
                if (seg == 0)      ap = h16 + (size_t)sidx[le] * HD + koff;
                else if (seg == 1) ap = h16 + (size_t)didx[le] * HD + koff;
                else               ap = ea + (size_t)min(eb + le, NE - 1) * HD + koff;
                a[mt] = *(const f16x8*)ap;
            }
#pragma unroll
            for (int nt = 0; nt < 4; ++nt) {
                f16x8 b = *(const f16x8*)&wlds[(nt * 4 + kt) * 512 + lane * 8];
#pragma unroll
                for (int mt = 0; mt < 4; ++mt)
                    acc[mt][nt] = MFMA16(a[mt], b, acc[mt][nt]);
            }
        }
    }
#pragma unroll
    for (int nt = 0; nt < 4; ++nt) {
        int col = nt * 16 + ln;
        if (col < 50) {
            float bv = mb1[col];
#pragma unroll
            for (int mt = 0; mt < 4; ++mt)
#pragma unroll
                for (int r = 0; r < 4; ++r) {
                    int le = wave * 64 + mt * 16 + q * 4 + r;
                    o1[le * 58 + col] = (f16)fmaxf(acc[mt][nt][r] + bv, 0.f);
                }
        }
    }
    __syncthreads();
    float o2[25];
#pragma unroll
    for (int ko = 0; ko < 25; ++ko) o2[ko] = b2l[ko];
    for (int k = 0; k < 50; ++k) {
        float a = (float)o1[tid * 58 + k];
#pragma unroll
        for (int ko = 0; ko < 25; ++ko) o2[ko] += a * w2l[k * 28 + ko];
    }
    float r0 = b3l[0], r1 = b3l[1];
#pragma unroll
    for (int ko = 0; ko < 25; ++ko) {
        float a = fmaxf(o2[ko], 0.f);
        r0 += a * w3l[ko * 2];
        r1 += a * w3l[ko * 2 + 1];
    }
    int e = eb + tid;
    if (e < NE) {
        float2 o; o.x = r0; o.y = r1;
        *(float2*)(out + (size_t)e * 2) = o;
    }
}

// ---------------------------------------------------------------------------
extern "C" void kernel_launch(void* const* d_in, const int* in_sizes, int n_in,
                              void* d_out, int out_size, void* d_ws, size_t ws_size,
                              hipStream_t stream) {
    const size_t WS_NEED = 197425936ULL;
    if (ws_size < WS_NEED) {
        hipMemsetAsync(d_out, 0, (size_t)out_size * 4, stream);
        return;
    }
    char* ws = (char*)d_ws;
    f16* ea = (f16*)(ws);
    f16* hf16 = (f16*)(ws + 128000000LL);
    f16* agg16 = (f16*)(ws + 140800000LL);
    f16* eattr16 = (f16*)(ws + 140800000LL);
    int* eord = (int*)(ws + 153600000LL);
    int* off = (int*)(ws + 155600000LL);
    int* cntcur = (int*)(ws + 155800064LL);
    int* bsum = (int*)(ws + 156000064LL);
    int* bpre = (int*)(ws + 156001088LL);
    f16* z2 = (f16*)(ws + 166400000LL);
    f16* xc = (f16*)(ws + 166400000LL);
    f16* tn = (f16*)(ws + 179200000LL);
    f16* wbuf = (f16*)(ws + 192000000LL);
    float* stats = (float*)(ws + 192475136LL);
    float* prm = (float*)(ws + 192476160LL);
    int* eix = (int*)(ws + 193425920LL);
    int* flags = (int*)(ws + 197425920LL);
    float* out = (float*)d_out;

    k_detect<<<1, 256, 0, stream>>>((const unsigned int*)d_in[2],
                                    (const int*)d_in[22], flags);
    k_cvt<<<6250, 256, 0, stream>>>(d_in[0], xc, 1600000, flags);
    k_cvt<<<7813, 256, 0, stream>>>(d_in[1], eattr16, 2000000, flags);
    k_cvt_prm<<<928, 256, 0, stream>>>(
        d_in[2], d_in[3], d_in[4], d_in[5], d_in[6], d_in[7], d_in[8], d_in[9],
        d_in[10], d_in[11], d_in[12], d_in[13], d_in[14], d_in[15], d_in[16],
        d_in[17], d_in[18], d_in[19], d_in[20], d_in[21], prm, flags);
    k_cvt_idx<<<3907, 256, 0, stream>>>((const int*)d_in[22], eix, flags);

    k_prep<<<928, 256, 0, stream>>>(prm, wbuf);
    k_node_lin<<<391, 256, 0, stream>>>(xc, wbuf, prm + P_NODE_B, hf16);
    k_edge_lin<<<7813, 256, 0, stream>>>(eattr16, prm + P_EDGE_W, prm + P_EDGE_B, ea);

    hipMemsetAsync(cntcur, 0, NN * 4, stream);
    k_hist<<<1954, 256, 0, stream>>>(eix, cntcur);
    k_scanA<<<196, 256, 0, stream>>>(cntcur, bsum);
    k_scanB<<<1, 256, 0, stream>>>(bsum, bpre, off);
    k_scanC<<<196, 256, 0, stream>>>(cntcur, bpre, off, cntcur);
    k_scatter<<<1954, 256, 0, stream>>>(eix, cntcur, eord);

    for (int l = 0; l < 2; ++l) {
        hipMemsetAsync(stats, 0, 1024, stream);
        k_agg<<<12500, 256, 0, stream>>>(ea, hf16, eix, off, eord, agg16);
        k_conv1<<<391, 256, 0, stream>>>(hf16, agg16, wbuf + (1 + l) * 16384,
                                         prm + P_CONV_B1 + l * HD, tn);
        k_conv2<<<391, 256, 0, stream>>>(tn, wbuf + (3 + l) * 16384,
                                         prm + P_CONV_B2 + l * HD, z2, stats);
        k_bn<<<6250, 256, 0, stream>>>(z2, stats, prm + P_GAMMA + l * HD,
                                       prm + P_BETA + l * HD, hf16);
        k_emlp<<<7813, 256, 0, stream>>>(hf16, eix, wbuf + (5 + l * 3) * 16384,
                                         prm + P_EMLP_B1 + l * HD,
                                         wbuf + (11 + l) * 16384,
                                         prm + P_EMLP_B2 + l * HD, ea);
    }
    k_readout<<<1954, 256, 0, stream>>>(hf16, ea, eix, wbuf + 13 * 16384,
                                        prm + P_MLP_B1, prm + P_MLP_W2,
                                        prm + P_MLP_B2, prm + P_MLP_W3,
                                        prm + P_MLP_B3, out);
}

// Round 7
// 1021.001 us; speedup vs baseline: 1.7035x; 1.0802x over previous
//
#include <hip/hip_runtime.h>

// GINe forward: N=50000 nodes, E=500000 edges, H=128, L=2 layers, C=2.
// fp32 inputs, int32 edge_index, fp32 output [E,2] (confirmed round 4).
// R7: k_emlp was ~55% LDS-pipe-bound. Transposed GEMMs (weights as A-operand,
// edges as N): 0.5 LDS reads/MFMA, t-tile via packed shuffles (no LDS tile),
// f16x4 vectorized ea RMW. LDS 33.8KB -> 4 blk/CU.

#define NN 50000
#define NE 500000
#define HD 128

typedef _Float16 f16;
typedef _Float16 f16x8 __attribute__((ext_vector_type(8)));
typedef _Float16 f16x4 __attribute__((ext_vector_type(4)));
typedef _Float16 f16x2 __attribute__((ext_vector_type(2)));
typedef float f32x4 __attribute__((ext_vector_type(4)));
typedef unsigned short ushort_t;

#define MFMA16(a, b, c) __builtin_amdgcn_mfma_f32_16x16x32_f16((a), (b), (c), 0, 0, 0)

#define TSTR 152

// f32 param blob offsets (element units)
#define P_NODE_W 0
#define P_NODE_B 16384
#define P_EDGE_W 16512
#define P_EDGE_B 18560
#define P_CONV_W1 18688
#define P_CONV_B1 51456
#define P_CONV_W2 51712
#define P_CONV_B2 84480
#define P_GAMMA 84736
#define P_BETA 84992
#define P_EMLP_W1 85248
#define P_EMLP_B1 183552
#define P_EMLP_W2 183808
#define P_EMLP_B2 216576
#define P_MLP_W1 216832
#define P_MLP_B1 236032
#define P_MLP_W2 236082
#define P_MLP_B2 237332
#define P_MLP_W3 237357
#define P_MLP_B3 237407
#define P_TOTAL 237409

__device__ __forceinline__ float bf2f(unsigned short u) {
    union { unsigned int i; float f; } v;
    v.i = ((unsigned int)u) << 16;
    return v.f;
}

// ---------------------------------------------------------------------------
__global__ __launch_bounds__(256) void k_detect(
    const unsigned int* nw, const int* ei, int* flags) {
    __shared__ int cF, cI;
    if (threadIdx.x == 0) { cF = 0; cI = 0; }
    __syncthreads();
    unsigned int u = nw[threadIdx.x];
    int e = (int)((u >> 7) & 0xFFu);
    int odd = ei[2 * threadIdx.x + 1];
    if (e >= 100 && e <= 140) atomicAdd(&cF, 1);
    if (odd != 0) atomicAdd(&cI, 1);
    __syncthreads();
    if (threadIdx.x == 0) {
        flags[0] = (cF < 160) ? 1 : 0;
        flags[1] = (cI < 64) ? 1 : 0;
    }
}

__global__ __launch_bounds__(256) void k_cvt(
    const void* src, f16* dst, int n4, const int* flags) {
    int i = blockIdx.x * 256 + threadIdx.x;
    if (i >= n4) return;
    f16x4 o;
    if (flags[0]) {
        float4 v = ((const float4*)src)[i];
        o[0] = (f16)v.x; o[1] = (f16)v.y; o[2] = (f16)v.z; o[3] = (f16)v.w;
    } else {
        ushort4 v = ((const ushort4*)src)[i];
        o[0] = (f16)bf2f(v.x); o[1] = (f16)bf2f(v.y);
        o[2] = (f16)bf2f(v.z); o[3] = (f16)bf2f(v.w);
    }
    ((f16x4*)dst)[i] = o;
}

__global__ __launch_bounds__(256) void k_cvt_prm(
    const void* p0, const void* p1, const void* p2, const void* p3,
    const void* p4, const void* p5, const void* p6, const void* p7,
    const void* p8, const void* p9, const void* p10, const void* p11,
    const void* p12, const void* p13, const void* p14, const void* p15,
    const void* p16, const void* p17, const void* p18, const void* p19,
    float* prm, const int* flags) {
    int i = blockIdx.x * 256 + threadIdx.x;
    if (i >= P_TOTAL) return;
    const int offs[21] = {P_NODE_W, P_NODE_B, P_EDGE_W, P_EDGE_B, P_CONV_W1,
                          P_CONV_B1, P_CONV_W2, P_CONV_B2, P_GAMMA, P_BETA,
                          P_EMLP_W1, P_EMLP_B1, P_EMLP_W2, P_EMLP_B2, P_MLP_W1,
                          P_MLP_B1, P_MLP_W2, P_MLP_B2, P_MLP_W3, P_MLP_B3,
                          P_TOTAL};
    const void* srcs[20] = {p0, p1, p2, p3, p4, p5, p6, p7, p8, p9, p10, p11,
                            p12, p13, p14, p15, p16, p17, p18, p19};
    int s = 0;
#pragma unroll
    for (int k = 1; k < 20; ++k)
        if (i >= offs[k]) s = k;
    int li = i - offs[s];
    float v = flags[0] ? ((const float*)srcs[s])[li]
                       : bf2f(((const ushort_t*)srcs[s])[li]);
    prm[i] = v;
}

__global__ __launch_bounds__(256) void k_cvt_idx(
    const int* src, int* dst, const int* flags) {
    int i = blockIdx.x * 256 + threadIdx.x;
    if (i >= 2 * NE) return;
    dst[i] = flags[1] ? src[2 * i] : src[i];
}

// ---------------------------------------------------------------------------
// CSR build: hist -> 3-phase exclusive scan -> scatter permutation.
// ---------------------------------------------------------------------------
__global__ __launch_bounds__(256) void k_hist(const int* eix, int* cnt) {
    int e = blockIdx.x * 256 + threadIdx.x;
    if (e < NE) atomicAdd(&cnt[eix[NE + e]], 1);
}

__global__ __launch_bounds__(256) void k_scanA(const int* cnt, int* bsum) {
    __shared__ int wsum[4];
    int tid = threadIdx.x;
    int i = blockIdx.x * 256 + tid;
    int v = (i < NN) ? cnt[i] : 0;
#pragma unroll
    for (int s = 1; s < 64; s <<= 1) v += __shfl_xor(v, s);
    if ((tid & 63) == 0) wsum[tid >> 6] = v;
    __syncthreads();
    if (tid == 0) bsum[blockIdx.x] = wsum[0] + wsum[1] + wsum[2] + wsum[3];
}

__global__ __launch_bounds__(256) void k_scanB(const int* bsum, int* bpre, int* off) {
    __shared__ int l[200];
    int tid = threadIdx.x;
    if (tid < 196) l[tid] = bsum[tid];
    __syncthreads();
    if (tid == 0) {
        int run = 0;
        for (int b = 0; b < 196; ++b) { int t = l[b]; l[b] = run; run += t; }
        off[NN] = run;
    }
    __syncthreads();
    if (tid < 196) bpre[tid] = l[tid];
}

__global__ __launch_bounds__(256) void k_scanC(
    const int* cnt, const int* bpre, int* off, int* cursor) {
    __shared__ int wsum[4];
    int tid = threadIdx.x;
    int lane = tid & 63, wave = tid >> 6;
    int i = blockIdx.x * 256 + tid;
    int v = (i < NN) ? cnt[i] : 0;
    int incl = v;
#pragma unroll
    for (int s = 1; s < 64; s <<= 1) {
        int t = __shfl_up(incl, s);
        if (lane >= s) incl += t;
    }
    if (lane == 63) wsum[wave] = incl;
    __syncthreads();
    int add = bpre[blockIdx.x];
    for (int w = 0; w < 4; ++w)
        if (w < wave) add += wsum[w];
    int excl = add + incl - v;
    if (i < NN) { off[i] = excl; cursor[i] = excl; }
}

__global__ __launch_bounds__(256) void k_scatter(
    const int* eix, int* cursor, int* eord) {
    int e = blockIdx.x * 256 + threadIdx.x;
    if (e >= NE) return;
    int d = eix[NE + e];
    int pos = atomicAdd(&cursor[d], 1);
    eord[pos] = e;
}

// ---------------------------------------------------------------------------
// CSR gather: agg[n] = sum_{e in in(n)} relu(h[src[e]] + ea[e]).
// ---------------------------------------------------------------------------
__global__ __launch_bounds__(256) void k_agg(
    const f16* ea, const f16* h16, const int* eix, const int* off,
    const int* eord, f16* agg16) {
    int wid = (blockIdx.x * 256 + threadIdx.x) >> 6;
    int lane = threadIdx.x & 63;
    int beg = off[wid], end = off[wid + 1];
    float a0 = 0.f, a1 = 0.f;
    for (int i = beg; i < end; ++i) {
        int e = eord[i];
        int s = eix[e];
        f16x2 ev = *(const f16x2*)(ea + (size_t)e * HD + lane * 2);
        f16x2 hv = *(const f16x2*)(h16 + (size_t)s * HD + lane * 2);
        a0 += fmaxf((float)ev[0] + (float)hv[0], 0.f);
        a1 += fmaxf((float)ev[1] + (float)hv[1], 0.f);
    }
    f16x2 o; o[0] = (f16)a0; o[1] = (f16)a1;
    *(f16x2*)(agg16 + (size_t)wid * HD + lane * 2) = o;
}

// ---------------------------------------------------------------------------
// Prep: swizzle all MFMA weight matrices into B-fragment order.
// (Same bytes serve as A-fragments of W^T: A[m=lane&15][k=q*8+j] = W[k][m].)
// ---------------------------------------------------------------------------
__global__ __launch_bounds__(256) void k_prep(const float* prm, f16* wbuf) {
    int gid = blockIdx.x * 256 + threadIdx.x;
    if (gid < 13 * 16384) {
        int seg = gid >> 14;
        int idx = gid & 16383;
        int off;
        switch (seg) {
            case 0: off = P_NODE_W; break;
            case 1: off = P_CONV_W1; break;
            case 2: off = P_CONV_W1 + 16384; break;
            case 3: off = P_CONV_W2; break;
            case 4: off = P_CONV_W2 + 16384; break;
            case 5: case 6: case 7: off = P_EMLP_W1 + (seg - 5) * 16384; break;
            case 8: case 9: case 10: off = P_EMLP_W1 + 49152 + (seg - 8) * 16384; break;
            case 11: off = P_EMLP_W2; break;
            default: off = P_EMLP_W2 + 16384; break;
        }
        int fb = idx >> 9;
        int sub = (idx & 511) >> 3;
        int j = idx & 7;
        int q = sub >> 4, n = sub & 15;
        int nt = fb >> 2, kt = fb & 3;
        int k = kt * 32 + q * 8 + j;
        int c = nt * 16 + n;
        wbuf[gid] = (f16)prm[off + k * 128 + c];
    } else {
        int t = gid - 13 * 16384;
        if (t >= 3 * 8192) return;
        int s = t >> 13;
        int idx = t & 8191;
        int fb = idx >> 9;
        int sub = (idx & 511) >> 3;
        int j = idx & 7;
        int q = sub >> 4, n = sub & 15;
        int nt = fb >> 2, kt = fb & 3;
        int k = s * 128 + kt * 32 + q * 8 + j;
        int c = nt * 16 + n;
        float v = (c < 50) ? prm[P_MLP_W1 + k * 50 + c] : 0.f;
        wbuf[13 * 16384 + s * 8192 + idx] = (f16)v;
    }
}

// ---------------------------------------------------------------------------
__global__ __launch_bounds__(256) void k_node_lin(
    const f16* xc, const f16* wT, const float* bias, f16* h_f16) {
    __shared__ __align__(16) f16 wlds[16384];
    int tid = threadIdx.x;
    {
        const uint4* s = (const uint4*)wT;
        uint4* d = (uint4*)wlds;
        for (int i = tid; i < 2048; i += 256) d[i] = s[i];
    }
    __syncthreads();
    int wave = tid >> 6, lane = tid & 63, q = lane >> 4, ln = lane & 15;
    int rowbase = blockIdx.x * 128 + wave * 32;
    f32x4 acc[2][8] = {};
#pragma unroll
    for (int kt = 0; kt < 4; ++kt) {
        int koff = kt * 32 + q * 8;
        f16x8 a[2];
#pragma unroll
        for (int mt = 0; mt < 2; ++mt) {
            int row = min(rowbase + mt * 16 + ln, NN - 1);
            a[mt] = *(const f16x8*)(xc + row * HD + koff);
        }
#pragma unroll
        for (int nt = 0; nt < 8; ++nt) {
            f16x8 b = *(const f16x8*)&wlds[(nt * 4 + kt) * 512 + lane * 8];
            acc[0][nt] = MFMA16(a[0], b, acc[0][nt]);
            acc[1][nt] = MFMA16(a[1], b, acc[1][nt]);
        }
    }
#pragma unroll
    for (int nt = 0; nt < 8; ++nt) {
        int col = nt * 16 + ln;
        float bv = bias[col];
#pragma unroll
        for (int mt = 0; mt < 2; ++mt)
#pragma unroll
            for (int r = 0; r < 4; ++r) {
                int row = rowbase + mt * 16 + q * 4 + r;
                if (row < NN) h_f16[row * HD + col] = (f16)(acc[mt][nt][r] + bv);
            }
    }
}

__global__ __launch_bounds__(256) void k_edge_lin(
    const f16* eattr, const float* ew, const float* ebias, f16* ea) {
    __shared__ float wl[16 * 128];
    __shared__ float bl[128];
    __shared__ float al[64 * 16];
    int tid = threadIdx.x;
    int eb = blockIdx.x * 64;
    for (int i = tid; i < 2048; i += 256) wl[i] = ew[i];
    if (tid < 128) bl[tid] = ebias[tid];
    {
        int e_l = tid >> 2, k0 = (tid & 3) * 4;
        int e = min(eb + e_l, NE - 1);
        f16x4 u = *(const f16x4*)(eattr + e * 16 + k0);
        al[e_l * 16 + k0 + 0] = (float)u[0];
        al[e_l * 16 + k0 + 1] = (float)u[1];
        al[e_l * 16 + k0 + 2] = (float)u[2];
        al[e_l * 16 + k0 + 3] = (float)u[3];
    }
    __syncthreads();
    for (int i = 0; i < 32; ++i) {
        int o = i * 256 + tid;
        int e_l = o >> 7, c = o & 127;
        float s = bl[c];
#pragma unroll
        for (int k = 0; k < 16; ++k) s += al[e_l * 16 + k] * wl[k * 128 + c];
        int e = eb + e_l;
        if (e < NE) ea[(size_t)e * HD + c] = (f16)s;
    }
}

// ---------------------------------------------------------------------------
// t_node = relu((h + agg) @ conv_w1 + b1)
// ---------------------------------------------------------------------------
__global__ __launch_bounds__(256) void k_conv1(
    const f16* h16, const f16* agg16, const f16* wT, const float* bias,
    f16* t_node) {
    __shared__ __align__(16) f16 wlds[16384];
    int tid = threadIdx.x;
    {
        const uint4* s = (const uint4*)wT;
        uint4* d = (uint4*)wlds;
        for (int i = tid; i < 2048; i += 256) d[i] = s[i];
    }
    __syncthreads();
    int wave = tid >> 6, lane = tid & 63, q = lane >> 4, ln = lane & 15;
    int rowbase = blockIdx.x * 128 + wave * 32;
    f32x4 acc[2][8] = {};
#pragma unroll
    for (int kt = 0; kt < 4; ++kt) {
        int koff = kt * 32 + q * 8;
        f16x8 a[2];
#pragma unroll
        for (int mt = 0; mt < 2; ++mt) {
            int row = min(rowbase + mt * 16 + ln, NN - 1);
            f16x8 hv = *(const f16x8*)(h16 + row * HD + koff);
            f16x8 gv = *(const f16x8*)(agg16 + row * HD + koff);
            f16x8 av;
#pragma unroll
            for (int j = 0; j < 8; ++j) av[j] = (f16)((float)hv[j] + (float)gv[j]);
            a[mt] = av;
        }
#pragma unroll
        for (int nt = 0; nt < 8; ++nt) {
            f16x8 b = *(const f16x8*)&wlds[(nt * 4 + kt) * 512 + lane * 8];
            acc[0][nt] = MFMA16(a[0], b, acc[0][nt]);
            acc[1][nt] = MFMA16(a[1], b, acc[1][nt]);
        }
    }
#pragma unroll
    for (int nt = 0; nt < 8; ++nt) {
        int col = nt * 16 + ln;
        float bv = bias[col];
#pragma unroll
        for (int mt = 0; mt < 2; ++mt)
#pragma unroll
            for (int r = 0; r < 4; ++r) {
                int row = rowbase + mt * 16 + q * 4 + r;
                if (row < NN)
                    t_node[row * HD + col] = (f16)fmaxf(acc[mt][nt][r] + bv, 0.f);
            }
    }
}

__global__ __launch_bounds__(256) void k_conv2(
    const f16* t_node, const f16* wT, const float* bias, f16* z2, float* stats) {
    __shared__ __align__(16) f16 wlds[16384];
    int tid = threadIdx.x;
    {
        const uint4* s = (const uint4*)wT;
        uint4* d = (uint4*)wlds;
        for (int i = tid; i < 2048; i += 256) d[i] = s[i];
    }
    __syncthreads();
    int wave = tid >> 6, lane = tid & 63, q = lane >> 4, ln = lane & 15;
    int rowbase = blockIdx.x * 128 + wave * 32;
    f32x4 acc[2][8] = {};
#pragma unroll
    for (int kt = 0; kt < 4; ++kt) {
        int koff = kt * 32 + q * 8;
        f16x8 a[2];
#pragma unroll
        for (int mt = 0; mt < 2; ++mt) {
            int row = min(rowbase + mt * 16 + ln, NN - 1);
            a[mt] = *(const f16x8*)(t_node + row * HD + koff);
        }
#pragma unroll
        for (int nt = 0; nt < 8; ++nt) {
            f16x8 b = *(const f16x8*)&wlds[(nt * 4 + kt) * 512 + lane * 8];
            acc[0][nt] = MFMA16(a[0], b, acc[0][nt]);
            acc[1][nt] = MFMA16(a[1], b, acc[1][nt]);
        }
    }
#pragma unroll
    for (int nt = 0; nt < 8; ++nt) {
        int col = nt * 16 + ln;
        float bv = bias[col];
        float s = 0.f, s2 = 0.f;
#pragma unroll
        for (int mt = 0; mt < 2; ++mt)
#pragma unroll
            for (int r = 0; r < 4; ++r) {
                int row = rowbase + mt * 16 + q * 4 + r;
                if (row < NN) {
                    float v = acc[mt][nt][r] + bv;
                    z2[row * HD + col] = (f16)v;
                    s += v;
                    s2 += v * v;
                }
            }
        s += __shfl_xor(s, 16);  s += __shfl_xor(s, 32);
        s2 += __shfl_xor(s2, 16); s2 += __shfl_xor(s2, 32);
        if (lane < 16) {
            atomicAdd(&stats[col], s);
            atomicAdd(&stats[HD + col], s2);
        }
    }
}

__global__ __launch_bounds__(256) void k_bn(
    const f16* z2, const float* stats, const float* gamma, const float* beta,
    f16* h16) {
    int gid = blockIdx.x * 256 + threadIdx.x;
    if (gid >= NN * HD / 4) return;
    int base = gid * 4;
    int c0 = base & (HD - 1);
    f16x4 z = *(const f16x4*)(z2 + base);
    f16x4 h = *(const f16x4*)(h16 + base);
    f16x4 ho;
#pragma unroll
    for (int j = 0; j < 4; ++j) {
        int c = c0 + j;
        float mu = stats[c] * (1.0f / NN);
        float var = stats[HD + c] * (1.0f / NN) - mu * mu;
        float zn = gamma[c] * ((float)z[j] - mu) * rsqrtf(var + 1e-5f) + beta[c];
        ho[j] = (f16)(((float)h[j] + fmaxf(zn, 0.f)) * 0.5f);
    }
    *(f16x4*)(h16 + base) = ho;
}

// ---------------------------------------------------------------------------
// Fused edge MLP (TRANSPOSED): ea^T += 0.5*(W2^T @ relu(W1^T @ featT + b1) + b2)
// Block = 128 edges, 4 waves; wave = 32 edges (2 n-tiles of 16) x 128 channels.
// A-operand = weight frags from LDS (shared across both n-tiles -> 0.5
// ds_read_b128/MFMA). GEMM1 C (t^T, 4 consecutive channels/reg) is repacked to
// GEMM2 B-frags with 64 packed __shfl (no LDS t-tile). Epilogue: f16x4 RMW.
// LDS = 32KB weights + 1KB idx -> 4 blocks/CU.
// ---------------------------------------------------------------------------
__global__ __launch_bounds__(256, 4) void k_emlp(
    const f16* h16, const int* eidx, const f16* w1T, const float* b1,
    const f16* w2T, const float* b2, f16* ea) {
    __shared__ __align__(16) f16 wlds[16384];
    __shared__ int sidx[128], didx[128];
    int tid = threadIdx.x;
    int eb = blockIdx.x * 128;
    if (tid < 128) {
        int e = min(eb + tid, NE - 1);
        sidx[tid] = eidx[e];
        didx[tid] = eidx[NE + e];
    }
    int wave = tid >> 6, lane = tid & 63, q = lane >> 4, ln = lane & 15;
    int el0 = wave * 32 + ln;
    int el1 = wave * 32 + 16 + ln;
    f32x4 acc[2][8] = {};
    for (int seg = 0; seg < 3; ++seg) {
        __syncthreads();
        {
            const uint4* s = (const uint4*)(w1T + seg * 16384);
            uint4* d = (uint4*)wlds;
            for (int i = tid; i < 2048; i += 256) d[i] = s[i];
        }
        __syncthreads();
        const f16 *p0, *p1;
        if (seg == 0) {
            p0 = h16 + (size_t)sidx[el0] * HD;
            p1 = h16 + (size_t)sidx[el1] * HD;
        } else if (seg == 1) {
            p0 = h16 + (size_t)didx[el0] * HD;
            p1 = h16 + (size_t)didx[el1] * HD;
        } else {
            p0 = ea + (size_t)min(eb + el0, NE - 1) * HD;
            p1 = ea + (size_t)min(eb + el1, NE - 1) * HD;
        }
        f16x8 g0[4], g1[4];
#pragma unroll
        for (int kt = 0; kt < 4; ++kt) {
            g0[kt] = *(const f16x8*)(p0 + kt * 32 + q * 8);
            g1[kt] = *(const f16x8*)(p1 + kt * 32 + q * 8);
        }
#pragma unroll
        for (int kt = 0; kt < 4; ++kt)
#pragma unroll
            for (int mt = 0; mt < 8; ++mt) {
                f16x8 a = *(const f16x8*)&wlds[(mt * 4 + kt) * 512 + lane * 8];
                acc[0][mt] = MFMA16(a, g0[kt], acc[0][mt]);
                acc[1][mt] = MFMA16(a, g1[kt], acc[1][mt]);
            }
    }
    // t^T = relu(acc + b1): lane holds channels mt*16+q*4+r of its edge.
    // Pack f16 pairs (mt=2kt lo, mt=2kt+1 hi) for the shuffle exchange.
    union HU { f16 h; unsigned short u; };
    unsigned int pk[2][4][4];
#pragma unroll
    for (int ntl = 0; ntl < 2; ++ntl)
#pragma unroll
        for (int kt = 0; kt < 4; ++kt) {
            f32x4 blo = *(const f32x4*)(b1 + (2 * kt) * 16 + q * 4);
            f32x4 bhi = *(const f32x4*)(b1 + (2 * kt + 1) * 16 + q * 4);
#pragma unroll
            for (int r = 0; r < 4; ++r) {
                HU lo, hi;
                lo.h = (f16)fmaxf(acc[ntl][2 * kt][r] + blo[r], 0.f);
                hi.h = (f16)fmaxf(acc[ntl][2 * kt + 1][r] + bhi[r], 0.f);
                pk[ntl][kt][r] =
                    (unsigned int)lo.u | ((unsigned int)hi.u << 16);
            }
        }
    __syncthreads();
    {
        const uint4* s = (const uint4*)w2T;
        uint4* d = (uint4*)wlds;
        for (int i = tid; i < 2048; i += 256) d[i] = s[i];
    }
    __syncthreads();
    // GEMM2: B-frag channel c = kt*32+q*8+j of own edge, fetched from lane
    // s1=((2q)&3)*16+ln (j=0..3) / s2=((2q+1)&3)*16+ln (j=4..7), half (q>>1).
    int s1 = (((2 * q) & 3) << 4) | ln;
    int s2 = (((2 * q + 1) & 3) << 4) | ln;
    int hsh = (q >> 1) * 16;
    f32x4 acc2[2][8] = {};
#pragma unroll
    for (int kt = 0; kt < 4; ++kt) {
        f16x8 bf[2];
#pragma unroll
        for (int ntl = 0; ntl < 2; ++ntl) {
            union { unsigned short u[8]; f16x8 v; } bb;
#pragma unroll
            for (int r = 0; r < 4; ++r) {
                unsigned int v1 = (unsigned int)__shfl((int)pk[ntl][kt][r], s1);
                unsigned int v2 = (unsigned int)__shfl((int)pk[ntl][kt][r], s2);
                bb.u[r] = (unsigned short)(v1 >> hsh);
                bb.u[4 + r] = (unsigned short)(v2 >> hsh);
            }
            bf[ntl] = bb.v;
        }
#pragma unroll
        for (int mt = 0; mt < 8; ++mt) {
            f16x8 a = *(const f16x8*)&wlds[(mt * 4 + kt) * 512 + lane * 8];
            acc2[0][mt] = MFMA16(a, bf[0], acc2[0][mt]);
            acc2[1][mt] = MFMA16(a, bf[1], acc2[1][mt]);
        }
    }
    // Epilogue: lane owns 4 consecutive channels per mt of its edge -> f16x4 RMW.
#pragma unroll
    for (int ntl = 0; ntl < 2; ++ntl) {
        int e = eb + wave * 32 + ntl * 16 + ln;
        if (e < NE) {
            f16* erow = ea + (size_t)e * HD;
#pragma unroll
            for (int mt = 0; mt < 8; ++mt) {
                int c0 = mt * 16 + q * 4;
                f32x4 bv = *(const f32x4*)(b2 + c0);
                f16x4 old = *(const f16x4*)(erow + c0);
                f16x4 nw;
#pragma unroll
                for (int r = 0; r < 4; ++r)
                    nw[r] = (f16)((float)old[r] +
                                  0.5f * (acc2[ntl][mt][r] + bv[r]));
                *(f16x4*)(erow + c0) = nw;
            }
        }
    }
}

// ---------------------------------------------------------------------------
__global__ __launch_bounds__(256) void k_readout(
    const f16* h16, const f16* ea, const int* eidx, const f16* w1Tp,
    const float* mb1, const float* mw2, const float* mb2,
    const float* mw3, const float* mb3, float* out) {
    __shared__ __align__(16) f16 wlds[8192];
    __shared__ f16 o1[256 * 58];
    __shared__ float w2l[50 * 28];
    __shared__ float w3l[50];
    __shared__ float b2l[25];
    __shared__ float b3l[2];
    __shared__ int sidx[256], didx[256];
    int tid = threadIdx.x;
    int eb = blockIdx.x * 256;
    {
        int e = min(eb + tid, NE - 1);
        sidx[tid] = eidx[e];
        didx[tid] = eidx[NE + e];
    }
    for (int i = tid; i < 50 * 28; i += 256) {
        int k = i / 28, ko = i - k * 28;
        w2l[i] = (ko < 25) ? mw2[k * 25 + ko] : 0.f;
    }
    if (tid < 50) w3l[tid] = mw3[tid];
    if (tid < 25) b2l[tid] = mb2[tid];
    if (tid < 2) b3l[tid] = mb3[tid];
    int wave = tid >> 6, lane = tid & 63, q = lane >> 4, ln = lane & 15;
    f32x4 acc[4][4] = {};
    for (int seg = 0; seg < 3; ++seg) {
        __syncthreads();
        {
            const uint4* s = (const uint4*)(w1Tp + seg * 8192);
            uint4* d = (uint4*)wlds;
            for (int i = tid; i < 1024; i += 256) d[i] = s[i];
        }
        __syncthreads();
#pragma unroll
        for (int kt = 0; kt < 4; ++kt) {
            int koff = kt * 32 + q * 8;
            f16x8 a[4];
#pragma unroll
            for (int mt = 0; mt < 4; ++mt) {
                int le = wave * 64 + mt * 16 + ln;
                const f16* ap;
                if (seg == 0)      ap = h16 + (size_t)sidx[le] * HD + koff;
                else if (seg == 1) ap = h16 + (size_t)didx[le] * HD + koff;
                else               ap = ea + (size_t)min(eb + le, NE - 1) * HD + koff;
                a[mt] = *(const f16x8*)ap;
            }
#pragma unroll
            for (int nt = 0; nt < 4; ++nt) {
                f16x8 b = *(const f16x8*)&wlds[(nt * 4 + kt) * 512 + lane * 8];
#pragma unroll
                for (int mt = 0; mt < 4; ++mt)
                    acc[mt][nt] = MFMA16(a[mt], b, acc[mt][nt]);
            }
        }
    }
#pragma unroll
    for (int nt = 0; nt < 4; ++nt) {
        int col = nt * 16 + ln;
        if (col < 50) {
            float bv = mb1[col];
#pragma unroll
            for (int mt = 0; mt < 4; ++mt)
#pragma unroll
                for (int r = 0; r < 4; ++r) {
                    int le = wave * 64 + mt * 16 + q * 4 + r;
                    o1[le * 58 + col] = (f16)fmaxf(acc[mt][nt][r] + bv, 0.f);
                }
        }
    }
    __syncthreads();
    float o2[25];
#pragma unroll
    for (int ko = 0; ko < 25; ++ko) o2[ko] = b2l[ko];
    for (int k = 0; k < 50; ++k) {
        float a = (float)o1[tid * 58 + k];
#pragma unroll
        for (int ko = 0; ko < 25; ++ko) o2[ko] += a * w2l[k * 28 + ko];
    }
    float r0 = b3l[0], r1 = b3l[1];
#pragma unroll
    for (int ko = 0; ko < 25; ++ko) {
        float a = fmaxf(o2[ko], 0.f);
        r0 += a * w3l[ko * 2];
        r1 += a * w3l[ko * 2 + 1];
    }
    int e = eb + tid;
    if (e < NE) {
        float2 o; o.x = r0; o.y = r1;
        *(float2*)(out + (size_t)e * 2) = o;
    }
}

// ---------------------------------------------------------------------------
extern "C" void kernel_launch(void* const* d_in, const int* in_sizes, int n_in,
                              void* d_out, int out_size, void* d_ws, size_t ws_size,
                              hipStream_t stream) {
    const size_t WS_NEED = 197425936ULL;
    if (ws_size < WS_NEED) {
        hipMemsetAsync(d_out, 0, (size_t)out_size * 4, stream);
        return;
    }
    char* ws = (char*)d_ws;
    f16* ea = (f16*)(ws);
    f16* hf16 = (f16*)(ws + 128000000LL);
    f16* agg16 = (f16*)(ws + 140800000LL);
    f16* eattr16 = (f16*)(ws + 140800000LL);
    int* eord = (int*)(ws + 153600000LL);
    int* off = (int*)(ws + 155600000LL);
    int* cntcur = (int*)(ws + 155800064LL);
    int* bsum = (int*)(ws + 156000064LL);
    int* bpre = (int*)(ws + 156001088LL);
    f16* z2 = (f16*)(ws + 166400000LL);
    f16* xc = (f16*)(ws + 166400000LL);
    f16* tn = (f16*)(ws + 179200000LL);
    f16* wbuf = (f16*)(ws + 192000000LL);
    float* stats = (float*)(ws + 192475136LL);
    float* prm = (float*)(ws + 192476160LL);
    int* eix = (int*)(ws + 193425920LL);
    int* flags = (int*)(ws + 197425920LL);
    float* out = (float*)d_out;

    k_detect<<<1, 256, 0, stream>>>((const unsigned int*)d_in[2],
                                    (const int*)d_in[22], flags);
    k_cvt<<<6250, 256, 0, stream>>>(d_in[0], xc, 1600000, flags);
    k_cvt<<<7813, 256, 0, stream>>>(d_in[1], eattr16, 2000000, flags);
    k_cvt_prm<<<928, 256, 0, stream>>>(
        d_in[2], d_in[3], d_in[4], d_in[5], d_in[6], d_in[7], d_in[8], d_in[9],
        d_in[10], d_in[11], d_in[12], d_in[13], d_in[14], d_in[15], d_in[16],
        d_in[17], d_in[18], d_in[19], d_in[20], d_in[21], prm, flags);
    k_cvt_idx<<<3907, 256, 0, stream>>>((const int*)d_in[22], eix, flags);

    k_prep<<<928, 256, 0, stream>>>(prm, wbuf);
    k_node_lin<<<391, 256, 0, stream>>>(xc, wbuf, prm + P_NODE_B, hf16);
    k_edge_lin<<<7813, 256, 0, stream>>>(eattr16, prm + P_EDGE_W, prm + P_EDGE_B, ea);

    hipMemsetAsync(cntcur, 0, NN * 4, stream);
    k_hist<<<1954, 256, 0, stream>>>(eix, cntcur);
    k_scanA<<<196, 256, 0, stream>>>(cntcur, bsum);
    k_scanB<<<1, 256, 0, stream>>>(bsum, bpre, off);
    k_scanC<<<196, 256, 0, stream>>>(cntcur, bpre, off, cntcur);
    k_scatter<<<1954, 256, 0, stream>>>(eix, cntcur, eord);

    for (int l = 0; l < 2; ++l) {
        hipMemsetAsync(stats, 0, 1024, stream);
        k_agg<<<12500, 256, 0, stream>>>(ea, hf16, eix, off, eord, agg16);
        k_conv1<<<391, 256, 0, stream>>>(hf16, agg16, wbuf + (1 + l) * 16384,
                                         prm + P_CONV_B1 + l * HD, tn);
        k_conv2<<<391, 256, 0, stream>>>(tn, wbuf + (3 + l) * 16384,
                                         prm + P_CONV_B2 + l * HD, z2, stats);
        k_bn<<<6250, 256, 0, stream>>>(z2, stats, prm + P_GAMMA + l * HD,
                                       prm + P_BETA + l * HD, hf16);
        k_emlp<<<3907, 256, 0, stream>>>(hf16, eix, wbuf + (5 + l * 3) * 16384,
                                         prm + P_EMLP_B1 + l * HD,
                                         wbuf + (11 + l) * 16384,
                                         prm + P_EMLP_B2 + l * HD, ea);
    }
    k_readout<<<1954, 256, 0, stream>>>(hf16, ea, eix, wbuf + 13 * 16384,
                                        prm + P_MLP_B1, prm + P_MLP_W2,
                                        prm + P_MLP_B2, prm + P_MLP_W3,
                                        prm + P_MLP_B3, out);
}

// Round 8
// 966.394 us; speedup vs baseline: 1.7997x; 1.0565x over previous
//
#include <hip/hip_runtime.h>

// GINe forward: N=50000 nodes, E=500000 edges, H=128, L=2 layers, C=2.
// fp32 inputs, int32 edge_index, fp32 output [E,2] (confirmed round 4).
// R8: edges physically sorted by dst (CSR order). ea lives in sorted order:
// k_agg reads ea sequentially; k_emlp/k_readout seg1 (h[dst]) gains locality;
// edge_lin gathers eattr via eord; readout scatters out via eord.

#define NN 50000
#define NE 500000
#define HD 128

typedef _Float16 f16;
typedef _Float16 f16x8 __attribute__((ext_vector_type(8)));
typedef _Float16 f16x4 __attribute__((ext_vector_type(4)));
typedef _Float16 f16x2 __attribute__((ext_vector_type(2)));
typedef float f32x4 __attribute__((ext_vector_type(4)));
typedef unsigned short ushort_t;

#define MFMA16(a, b, c) __builtin_amdgcn_mfma_f32_16x16x32_f16((a), (b), (c), 0, 0, 0)

// f32 param blob offsets (element units)
#define P_NODE_W 0
#define P_NODE_B 16384
#define P_EDGE_W 16512
#define P_EDGE_B 18560
#define P_CONV_W1 18688
#define P_CONV_B1 51456
#define P_CONV_W2 51712
#define P_CONV_B2 84480
#define P_GAMMA 84736
#define P_BETA 84992
#define P_EMLP_W1 85248
#define P_EMLP_B1 183552
#define P_EMLP_W2 183808
#define P_EMLP_B2 216576
#define P_MLP_W1 216832
#define P_MLP_B1 236032
#define P_MLP_W2 236082
#define P_MLP_B2 237332
#define P_MLP_W3 237357
#define P_MLP_B3 237407
#define P_TOTAL 237409

__device__ __forceinline__ float bf2f(unsigned short u) {
    union { unsigned int i; float f; } v;
    v.i = ((unsigned int)u) << 16;
    return v.f;
}

// ---------------------------------------------------------------------------
__global__ __launch_bounds__(256) void k_detect(
    const unsigned int* nw, const int* ei, int* flags) {
    __shared__ int cF, cI;
    if (threadIdx.x == 0) { cF = 0; cI = 0; }
    __syncthreads();
    unsigned int u = nw[threadIdx.x];
    int e = (int)((u >> 7) & 0xFFu);
    int odd = ei[2 * threadIdx.x + 1];
    if (e >= 100 && e <= 140) atomicAdd(&cF, 1);
    if (odd != 0) atomicAdd(&cI, 1);
    __syncthreads();
    if (threadIdx.x == 0) {
        flags[0] = (cF < 160) ? 1 : 0;
        flags[1] = (cI < 64) ? 1 : 0;
    }
}

__global__ __launch_bounds__(256) void k_cvt(
    const void* src, f16* dst, int n4, const int* flags) {
    int i = blockIdx.x * 256 + threadIdx.x;
    if (i >= n4) return;
    f16x4 o;
    if (flags[0]) {
        float4 v = ((const float4*)src)[i];
        o[0] = (f16)v.x; o[1] = (f16)v.y; o[2] = (f16)v.z; o[3] = (f16)v.w;
    } else {
        ushort4 v = ((const ushort4*)src)[i];
        o[0] = (f16)bf2f(v.x); o[1] = (f16)bf2f(v.y);
        o[2] = (f16)bf2f(v.z); o[3] = (f16)bf2f(v.w);
    }
    ((f16x4*)dst)[i] = o;
}

__global__ __launch_bounds__(256) void k_cvt_prm(
    const void* p0, const void* p1, const void* p2, const void* p3,
    const void* p4, const void* p5, const void* p6, const void* p7,
    const void* p8, const void* p9, const void* p10, const void* p11,
    const void* p12, const void* p13, const void* p14, const void* p15,
    const void* p16, const void* p17, const void* p18, const void* p19,
    float* prm, const int* flags) {
    int i = blockIdx.x * 256 + threadIdx.x;
    if (i >= P_TOTAL) return;
    const int offs[21] = {P_NODE_W, P_NODE_B, P_EDGE_W, P_EDGE_B, P_CONV_W1,
                          P_CONV_B1, P_CONV_W2, P_CONV_B2, P_GAMMA, P_BETA,
                          P_EMLP_W1, P_EMLP_B1, P_EMLP_W2, P_EMLP_B2, P_MLP_W1,
                          P_MLP_B1, P_MLP_W2, P_MLP_B2, P_MLP_W3, P_MLP_B3,
                          P_TOTAL};
    const void* srcs[20] = {p0, p1, p2, p3, p4, p5, p6, p7, p8, p9, p10, p11,
                            p12, p13, p14, p15, p16, p17, p18, p19};
    int s = 0;
#pragma unroll
    for (int k = 1; k < 20; ++k)
        if (i >= offs[k]) s = k;
    int li = i - offs[s];
    float v = flags[0] ? ((const float*)srcs[s])[li]
                       : bf2f(((const ushort_t*)srcs[s])[li]);
    prm[i] = v;
}

__global__ __launch_bounds__(256) void k_cvt_idx(
    const int* src, int* dst, const int* flags) {
    int i = blockIdx.x * 256 + threadIdx.x;
    if (i >= 2 * NE) return;
    dst[i] = flags[1] ? src[2 * i] : src[i];
}

// ---------------------------------------------------------------------------
// CSR build: hist -> 3-phase exclusive scan -> scatter permutation.
// ---------------------------------------------------------------------------
__global__ __launch_bounds__(256) void k_hist(const int* eix, int* cnt) {
    int e = blockIdx.x * 256 + threadIdx.x;
    if (e < NE) atomicAdd(&cnt[eix[NE + e]], 1);
}

__global__ __launch_bounds__(256) void k_scanA(const int* cnt, int* bsum) {
    __shared__ int wsum[4];
    int tid = threadIdx.x;
    int i = blockIdx.x * 256 + tid;
    int v = (i < NN) ? cnt[i] : 0;
#pragma unroll
    for (int s = 1; s < 64; s <<= 1) v += __shfl_xor(v, s);
    if ((tid & 63) == 0) wsum[tid >> 6] = v;
    __syncthreads();
    if (tid == 0) bsum[blockIdx.x] = wsum[0] + wsum[1] + wsum[2] + wsum[3];
}

__global__ __launch_bounds__(256) void k_scanB(const int* bsum, int* bpre, int* off) {
    __shared__ int l[200];
    int tid = threadIdx.x;
    if (tid < 196) l[tid] = bsum[tid];
    __syncthreads();
    if (tid == 0) {
        int run = 0;
        for (int b = 0; b < 196; ++b) { int t = l[b]; l[b] = run; run += t; }
        off[NN] = run;
    }
    __syncthreads();
    if (tid < 196) bpre[tid] = l[tid];
}

__global__ __launch_bounds__(256) void k_scanC(
    const int* cnt, const int* bpre, int* off, int* cursor) {
    __shared__ int wsum[4];
    int tid = threadIdx.x;
    int lane = tid & 63, wave = tid >> 6;
    int i = blockIdx.x * 256 + tid;
    int v = (i < NN) ? cnt[i] : 0;
    int incl = v;
#pragma unroll
    for (int s = 1; s < 64; s <<= 1) {
        int t = __shfl_up(incl, s);
        if (lane >= s) incl += t;
    }
    if (lane == 63) wsum[wave] = incl;
    __syncthreads();
    int add = bpre[blockIdx.x];
    for (int w = 0; w < 4; ++w)
        if (w < wave) add += wsum[w];
    int excl = add + incl - v;
    if (i < NN) { off[i] = excl; cursor[i] = excl; }
}

__global__ __launch_bounds__(256) void k_scatter(
    const int* eix, int* cursor, int* eord) {
    int e = blockIdx.x * 256 + threadIdx.x;
    if (e >= NE) return;
    int d = eix[NE + e];
    int pos = atomicAdd(&cursor[d], 1);
    eord[pos] = e;
}

// Sorted index arrays: ssrc[i]/sdst[i] = src/dst of sorted edge i.
__global__ __launch_bounds__(256) void k_gidx(
    const int* eix, const int* eord, int* ssrc, int* sdst) {
    int i = blockIdx.x * 256 + threadIdx.x;
    if (i >= NE) return;
    int e = eord[i];
    ssrc[i] = eix[e];
    sdst[i] = eix[NE + e];
}

// ---------------------------------------------------------------------------
// CSR gather (sorted ea): agg[n] = sum_{i in off[n]..off[n+1]} relu(h[ssrc[i]]+ea[i])
// ea rows are read fully sequentially.
// ---------------------------------------------------------------------------
__global__ __launch_bounds__(256) void k_agg(
    const f16* ea, const f16* h16, const int* ssrc, const int* off, f16* agg16) {
    int wid = (blockIdx.x * 256 + threadIdx.x) >> 6;
    int lane = threadIdx.x & 63;
    int beg = off[wid], end = off[wid + 1];
    float a0 = 0.f, a1 = 0.f;
    for (int i = beg; i < end; ++i) {
        int s = ssrc[i];
        f16x2 ev = *(const f16x2*)(ea + (size_t)i * HD + lane * 2);
        f16x2 hv = *(const f16x2*)(h16 + (size_t)s * HD + lane * 2);
        a0 += fmaxf((float)ev[0] + (float)hv[0], 0.f);
        a1 += fmaxf((float)ev[1] + (float)hv[1], 0.f);
    }
    f16x2 o; o[0] = (f16)a0; o[1] = (f16)a1;
    *(f16x2*)(agg16 + (size_t)wid * HD + lane * 2) = o;
}

// ---------------------------------------------------------------------------
// Prep: swizzle all MFMA weight matrices into B-fragment order.
// ---------------------------------------------------------------------------
__global__ __launch_bounds__(256) void k_prep(const float* prm, f16* wbuf) {
    int gid = blockIdx.x * 256 + threadIdx.x;
    if (gid < 13 * 16384) {
        int seg = gid >> 14;
        int idx = gid & 16383;
        int off;
        switch (seg) {
            case 0: off = P_NODE_W; break;
            case 1: off = P_CONV_W1; break;
            case 2: off = P_CONV_W1 + 16384; break;
            case 3: off = P_CONV_W2; break;
            case 4: off = P_CONV_W2 + 16384; break;
            case 5: case 6: case 7: off = P_EMLP_W1 + (seg - 5) * 16384; break;
            case 8: case 9: case 10: off = P_EMLP_W1 + 49152 + (seg - 8) * 16384; break;
            case 11: off = P_EMLP_W2; break;
            default: off = P_EMLP_W2 + 16384; break;
        }
        int fb = idx >> 9;
        int sub = (idx & 511) >> 3;
        int j = idx & 7;
        int q = sub >> 4, n = sub & 15;
        int nt = fb >> 2, kt = fb & 3;
        int k = kt * 32 + q * 8 + j;
        int c = nt * 16 + n;
        wbuf[gid] = (f16)prm[off + k * 128 + c];
    } else {
        int t = gid - 13 * 16384;
        if (t >= 3 * 8192) return;
        int s = t >> 13;
        int idx = t & 8191;
        int fb = idx >> 9;
        int sub = (idx & 511) >> 3;
        int j = idx & 7;
        int q = sub >> 4, n = sub & 15;
        int nt = fb >> 2, kt = fb & 3;
        int k = s * 128 + kt * 32 + q * 8 + j;
        int c = nt * 16 + n;
        float v = (c < 50) ? prm[P_MLP_W1 + k * 50 + c] : 0.f;
        wbuf[13 * 16384 + s * 8192 + idx] = (f16)v;
    }
}

// ---------------------------------------------------------------------------
__global__ __launch_bounds__(256) void k_node_lin(
    const f16* xc, const f16* wT, const float* bias, f16* h_f16) {
    __shared__ __align__(16) f16 wlds[16384];
    int tid = threadIdx.x;
    {
        const uint4* s = (const uint4*)wT;
        uint4* d = (uint4*)wlds;
        for (int i = tid; i < 2048; i += 256) d[i] = s[i];
    }
    __syncthreads();
    int wave = tid >> 6, lane = tid & 63, q = lane >> 4, ln = lane & 15;
    int rowbase = blockIdx.x * 128 + wave * 32;
    f32x4 acc[2][8] = {};
#pragma unroll
    for (int kt = 0; kt < 4; ++kt) {
        int koff = kt * 32 + q * 8;
        f16x8 a[2];
#pragma unroll
        for (int mt = 0; mt < 2; ++mt) {
            int row = min(rowbase + mt * 16 + ln, NN - 1);
            a[mt] = *(const f16x8*)(xc + row * HD + koff);
        }
#pragma unroll
        for (int nt = 0; nt < 8; ++nt) {
            f16x8 b = *(const f16x8*)&wlds[(nt * 4 + kt) * 512 + lane * 8];
            acc[0][nt] = MFMA16(a[0], b, acc[0][nt]);
            acc[1][nt] = MFMA16(a[1], b, acc[1][nt]);
        }
    }
#pragma unroll
    for (int nt = 0; nt < 8; ++nt) {
        int col = nt * 16 + ln;
        float bv = bias[col];
#pragma unroll
        for (int mt = 0; mt < 2; ++mt)
#pragma unroll
            for (int r = 0; r < 4; ++r) {
                int row = rowbase + mt * 16 + q * 4 + r;
                if (row < NN) h_f16[row * HD + col] = (f16)(acc[mt][nt][r] + bv);
            }
    }
}

// ea (sorted) = edge_attr[eord[p]] @ edge_w + edge_b
__global__ __launch_bounds__(256) void k_edge_lin(
    const f16* eattr, const float* ew, const float* ebias, const int* eord,
    f16* ea) {
    __shared__ float wl[16 * 128];
    __shared__ float bl[128];
    __shared__ float al[64 * 16];
    int tid = threadIdx.x;
    int eb = blockIdx.x * 64;
    for (int i = tid; i < 2048; i += 256) wl[i] = ew[i];
    if (tid < 128) bl[tid] = ebias[tid];
    {
        int e_l = tid >> 2, k0 = (tid & 3) * 4;
        int er = eord[min(eb + e_l, NE - 1)];
        f16x4 u = *(const f16x4*)(eattr + er * 16 + k0);
        al[e_l * 16 + k0 + 0] = (float)u[0];
        al[e_l * 16 + k0 + 1] = (float)u[1];
        al[e_l * 16 + k0 + 2] = (float)u[2];
        al[e_l * 16 + k0 + 3] = (float)u[3];
    }
    __syncthreads();
    for (int i = 0; i < 32; ++i) {
        int o = i * 256 + tid;
        int e_l = o >> 7, c = o & 127;
        float s = bl[c];
#pragma unroll
        for (int k = 0; k < 16; ++k) s += al[e_l * 16 + k] * wl[k * 128 + c];
        int e = eb + e_l;
        if (e < NE) ea[(size_t)e * HD + c] = (f16)s;
    }
}

// ---------------------------------------------------------------------------
// t_node = relu((h + agg) @ conv_w1 + b1)
// ---------------------------------------------------------------------------
__global__ __launch_bounds__(256) void k_conv1(
    const f16* h16, const f16* agg16, const f16* wT, const float* bias,
    f16* t_node) {
    __shared__ __align__(16) f16 wlds[16384];
    int tid = threadIdx.x;
    {
        const uint4* s = (const uint4*)wT;
        uint4* d = (uint4*)wlds;
        for (int i = tid; i < 2048; i += 256) d[i] = s[i];
    }
    __syncthreads();
    int wave = tid >> 6, lane = tid & 63, q = lane >> 4, ln = lane & 15;
    int rowbase = blockIdx.x * 128 + wave * 32;
    f32x4 acc[2][8] = {};
#pragma unroll
    for (int kt = 0; kt < 4; ++kt) {
        int koff = kt * 32 + q * 8;
        f16x8 a[2];
#pragma unroll
        for (int mt = 0; mt < 2; ++mt) {
            int row = min(rowbase + mt * 16 + ln, NN - 1);
            f16x8 hv = *(const f16x8*)(h16 + row * HD + koff);
            f16x8 gv = *(const f16x8*)(agg16 + row * HD + koff);
            f16x8 av;
#pragma unroll
            for (int j = 0; j < 8; ++j) av[j] = (f16)((float)hv[j] + (float)gv[j]);
            a[mt] = av;
        }
#pragma unroll
        for (int nt = 0; nt < 8; ++nt) {
            f16x8 b = *(const f16x8*)&wlds[(nt * 4 + kt) * 512 + lane * 8];
            acc[0][nt] = MFMA16(a[0], b, acc[0][nt]);
            acc[1][nt] = MFMA16(a[1], b, acc[1][nt]);
        }
    }
#pragma unroll
    for (int nt = 0; nt < 8; ++nt) {
        int col = nt * 16 + ln;
        float bv = bias[col];
#pragma unroll
        for (int mt = 0; mt < 2; ++mt)
#pragma unroll
            for (int r = 0; r < 4; ++r) {
                int row = rowbase + mt * 16 + q * 4 + r;
                if (row < NN)
                    t_node[row * HD + col] = (f16)fmaxf(acc[mt][nt][r] + bv, 0.f);
            }
    }
}

__global__ __launch_bounds__(256) void k_conv2(
    const f16* t_node, const f16* wT, const float* bias, f16* z2, float* stats) {
    __shared__ __align__(16) f16 wlds[16384];
    int tid = threadIdx.x;
    {
        const uint4* s = (const uint4*)wT;
        uint4* d = (uint4*)wlds;
        for (int i = tid; i < 2048; i += 256) d[i] = s[i];
    }
    __syncthreads();
    int wave = tid >> 6, lane = tid & 63, q = lane >> 4, ln = lane & 15;
    int rowbase = blockIdx.x * 128 + wave * 32;
    f32x4 acc[2][8] = {};
#pragma unroll
    for (int kt = 0; kt < 4; ++kt) {
        int koff = kt * 32 + q * 8;
        f16x8 a[2];
#pragma unroll
        for (int mt = 0; mt < 2; ++mt) {
            int row = min(rowbase + mt * 16 + ln, NN - 1);
            a[mt] = *(const f16x8*)(t_node + row * HD + koff);
        }
#pragma unroll
        for (int nt = 0; nt < 8; ++nt) {
            f16x8 b = *(const f16x8*)&wlds[(nt * 4 + kt) * 512 + lane * 8];
            acc[0][nt] = MFMA16(a[0], b, acc[0][nt]);
            acc[1][nt] = MFMA16(a[1], b, acc[1][nt]);
        }
    }
#pragma unroll
    for (int nt = 0; nt < 8; ++nt) {
        int col = nt * 16 + ln;
        float bv = bias[col];
        float s = 0.f, s2 = 0.f;
#pragma unroll
        for (int mt = 0; mt < 2; ++mt)
#pragma unroll
            for (int r = 0; r < 4; ++r) {
                int row = rowbase + mt * 16 + q * 4 + r;
                if (row < NN) {
                    float v = acc[mt][nt][r] + bv;
                    z2[row * HD + col] = (f16)v;
                    s += v;
                    s2 += v * v;
                }
            }
        s += __shfl_xor(s, 16);  s += __shfl_xor(s, 32);
        s2 += __shfl_xor(s2, 16); s2 += __shfl_xor(s2, 32);
        if (lane < 16) {
            atomicAdd(&stats[col], s);
            atomicAdd(&stats[HD + col], s2);
        }
    }
}

__global__ __launch_bounds__(256) void k_bn(
    const f16* z2, const float* stats, const float* gamma, const float* beta,
    f16* h16) {
    int gid = blockIdx.x * 256 + threadIdx.x;
    if (gid >= NN * HD / 4) return;
    int base = gid * 4;
    int c0 = base & (HD - 1);
    f16x4 z = *(const f16x4*)(z2 + base);
    f16x4 h = *(const f16x4*)(h16 + base);
    f16x4 ho;
#pragma unroll
    for (int j = 0; j < 4; ++j) {
        int c = c0 + j;
        float mu = stats[c] * (1.0f / NN);
        float var = stats[HD + c] * (1.0f / NN) - mu * mu;
        float zn = gamma[c] * ((float)z[j] - mu) * rsqrtf(var + 1e-5f) + beta[c];
        ho[j] = (f16)(((float)h[j] + fmaxf(zn, 0.f)) * 0.5f);
    }
    *(f16x4*)(h16 + base) = ho;
}

// ---------------------------------------------------------------------------
// Fused edge MLP (TRANSPOSED, sorted edges):
// ea^T += 0.5*(W2^T @ relu(W1^T @ featT + b1) + b2). Same structure as R7 but
// src/dst from sorted arrays (seg1 dst-sorted -> cache locality).
// ---------------------------------------------------------------------------
__global__ __launch_bounds__(256, 4) void k_emlp(
    const f16* h16, const int* ssrc, const int* sdst, const f16* w1T,
    const float* b1, const f16* w2T, const float* b2, f16* ea) {
    __shared__ __align__(16) f16 wlds[16384];
    int tid = threadIdx.x;
    int eb = blockIdx.x * 128;
    int wave = tid >> 6, lane = tid & 63, q = lane >> 4, ln = lane & 15;
    int g0 = min(eb + wave * 32 + ln, NE - 1);
    int g1 = min(eb + wave * 32 + 16 + ln, NE - 1);
    int is0 = ssrc[g0], is1 = ssrc[g1];
    int id0 = sdst[g0], id1 = sdst[g1];
    f32x4 acc[2][8] = {};
    for (int seg = 0; seg < 3; ++seg) {
        __syncthreads();
        {
            const uint4* s = (const uint4*)(w1T + seg * 16384);
            uint4* d = (uint4*)wlds;
            for (int i = tid; i < 2048; i += 256) d[i] = s[i];
        }
        __syncthreads();
        const f16 *p0, *p1;
        if (seg == 0) {
            p0 = h16 + (size_t)is0 * HD;
            p1 = h16 + (size_t)is1 * HD;
        } else if (seg == 1) {
            p0 = h16 + (size_t)id0 * HD;
            p1 = h16 + (size_t)id1 * HD;
        } else {
            p0 = ea + (size_t)g0 * HD;
            p1 = ea + (size_t)g1 * HD;
        }
        f16x8 f0[4], f1[4];
#pragma unroll
        for (int kt = 0; kt < 4; ++kt) {
            f0[kt] = *(const f16x8*)(p0 + kt * 32 + q * 8);
            f1[kt] = *(const f16x8*)(p1 + kt * 32 + q * 8);
        }
#pragma unroll
        for (int kt = 0; kt < 4; ++kt)
#pragma unroll
            for (int mt = 0; mt < 8; ++mt) {
                f16x8 a = *(const f16x8*)&wlds[(mt * 4 + kt) * 512 + lane * 8];
                acc[0][mt] = MFMA16(a, f0[kt], acc[0][mt]);
                acc[1][mt] = MFMA16(a, f1[kt], acc[1][mt]);
            }
    }
    // t^T = relu(acc + b1), packed for shuffle exchange.
    union HU { f16 h; unsigned short u; };
    unsigned int pk[2][4][4];
#pragma unroll
    for (int ntl = 0; ntl < 2; ++ntl)
#pragma unroll
        for (int kt = 0; kt < 4; ++kt) {
            f32x4 blo = *(const f32x4*)(b1 + (2 * kt) * 16 + q * 4);
            f32x4 bhi = *(const f32x4*)(b1 + (2 * kt + 1) * 16 + q * 4);
#pragma unroll
            for (int r = 0; r < 4; ++r) {
                HU lo, hi;
                lo.h = (f16)fmaxf(acc[ntl][2 * kt][r] + blo[r], 0.f);
                hi.h = (f16)fmaxf(acc[ntl][2 * kt + 1][r] + bhi[r], 0.f);
                pk[ntl][kt][r] =
                    (unsigned int)lo.u | ((unsigned int)hi.u << 16);
            }
        }
    __syncthreads();
    {
        const uint4* s = (const uint4*)w2T;
        uint4* d = (uint4*)wlds;
        for (int i = tid; i < 2048; i += 256) d[i] = s[i];
    }
    __syncthreads();
    int s1 = (((2 * q) & 3) << 4) | ln;
    int s2 = (((2 * q + 1) & 3) << 4) | ln;
    int hsh = (q >> 1) * 16;
    f32x4 acc2[2][8] = {};
#pragma unroll
    for (int kt = 0; kt < 4; ++kt) {
        f16x8 bf[2];
#pragma unroll
        for (int ntl = 0; ntl < 2; ++ntl) {
            union { unsigned short u[8]; f16x8 v; } bb;
#pragma unroll
            for (int r = 0; r < 4; ++r) {
                unsigned int v1 = (unsigned int)__shfl((int)pk[ntl][kt][r], s1);
                unsigned int v2 = (unsigned int)__shfl((int)pk[ntl][kt][r], s2);
                bb.u[r] = (unsigned short)(v1 >> hsh);
                bb.u[4 + r] = (unsigned short)(v2 >> hsh);
            }
            bf[ntl] = bb.v;
        }
#pragma unroll
        for (int mt = 0; mt < 8; ++mt) {
            f16x8 a = *(const f16x8*)&wlds[(mt * 4 + kt) * 512 + lane * 8];
            acc2[0][mt] = MFMA16(a, bf[0], acc2[0][mt]);
            acc2[1][mt] = MFMA16(a, bf[1], acc2[1][mt]);
        }
    }
#pragma unroll
    for (int ntl = 0; ntl < 2; ++ntl) {
        int e = eb + wave * 32 + ntl * 16 + ln;
        if (e < NE) {
            f16* erow = ea + (size_t)e * HD;
#pragma unroll
            for (int mt = 0; mt < 8; ++mt) {
                int c0 = mt * 16 + q * 4;
                f32x4 bv = *(const f32x4*)(b2 + c0);
                f16x4 old = *(const f16x4*)(erow + c0);
                f16x4 nw;
#pragma unroll
                for (int r = 0; r < 4; ++r)
                    nw[r] = (f16)((float)old[r] +
                                  0.5f * (acc2[ntl][mt][r] + bv[r]));
                *(f16x4*)(erow + c0) = nw;
            }
        }
    }
}

// ---------------------------------------------------------------------------
// Readout (sorted edges, scattered final store via eord).
// ---------------------------------------------------------------------------
__global__ __launch_bounds__(256) void k_readout(
    const f16* h16, const f16* ea, const int* ssrc, const int* sdst,
    const int* eord, const f16* w1Tp, const float* mb1, const float* mw2,
    const float* mb2, const float* mw3, const float* mb3, float* out) {
    __shared__ __align__(16) f16 wlds[8192];
    __shared__ f16 o1[256 * 58];
    __shared__ float w2l[50 * 28];
    __shared__ float w3l[50];
    __shared__ float b2l[25];
    __shared__ float b3l[2];
    __shared__ int sidx[256], didx[256];
    int tid = threadIdx.x;
    int eb = blockIdx.x * 256;
    {
        int e = min(eb + tid, NE - 1);
        sidx[tid] = ssrc[e];
        didx[tid] = sdst[e];
    }
    for (int i = tid; i < 50 * 28; i += 256) {
        int k = i / 28, ko = i - k * 28;
        w2l[i] = (ko < 25) ? mw2[k * 25 + ko] : 0.f;
    }
    if (tid < 50) w3l[tid] = mw3[tid];
    if (tid < 25) b2l[tid] = mb2[tid];
    if (tid < 2) b3l[tid] = mb3[tid];
    int wave = tid >> 6, lane = tid & 63, q = lane >> 4, ln = lane & 15;
    f32x4 acc[4][4] = {};
    for (int seg = 0; seg < 3; ++seg) {
        __syncthreads();
        {
            const uint4* s = (const uint4*)(w1Tp + seg * 8192);
            uint4* d = (uint4*)wlds;
            for (int i = tid; i < 1024; i += 256) d[i] = s[i];
        }
        __syncthreads();
#pragma unroll
        for (int kt = 0; kt < 4; ++kt) {
            int koff = kt * 32 + q * 8;
            f16x8 a[4];
#pragma unroll
            for (int mt = 0; mt < 4; ++mt) {
                int le = wave * 64 + mt * 16 + ln;
                const f16* ap;
                if (seg == 0)      ap = h16 + (size_t)sidx[le] * HD + koff;
                else if (seg == 1) ap = h16 + (size_t)didx[le] * HD + koff;
                else               ap = ea + (size_t)min(eb + le, NE - 1) * HD + koff;
                a[mt] = *(const f16x8*)ap;
            }
#pragma unroll
            for (int nt = 0; nt < 4; ++nt) {
                f16x8 b = *(const f16x8*)&wlds[(nt * 4 + kt) * 512 + lane * 8];
#pragma unroll
                for (int mt = 0; mt < 4; ++mt)
                    acc[mt][nt] = MFMA16(a[mt], b, acc[mt][nt]);
            }
        }
    }
#pragma unroll
    for (int nt = 0; nt < 4; ++nt) {
        int col = nt * 16 + ln;
        if (col < 50) {
            float bv = mb1[col];
#pragma unroll
            for (int mt = 0; mt < 4; ++mt)
#pragma unroll
                for (int r = 0; r < 4; ++r) {
                    int le = wave * 64 + mt * 16 + q * 4 + r;
                    o1[le * 58 + col] = (f16)fmaxf(acc[mt][nt][r] + bv, 0.f);
                }
        }
    }
    __syncthreads();
    float o2[25];
#pragma unroll
    for (int ko = 0; ko < 25; ++ko) o2[ko] = b2l[ko];
    for (int k = 0; k < 50; ++k) {
        float a = (float)o1[tid * 58 + k];
#pragma unroll
        for (int ko = 0; ko < 25; ++ko) o2[ko] += a * w2l[k * 28 + ko];
    }
    float r0 = b3l[0], r1 = b3l[1];
#pragma unroll
    for (int ko = 0; ko < 25; ++ko) {
        float a = fmaxf(o2[ko], 0.f);
        r0 += a * w3l[ko * 2];
        r1 += a * w3l[ko * 2 + 1];
    }
    int e = eb + tid;
    if (e < NE) {
        int oe = eord[e];
        float2 o; o.x = r0; o.y = r1;
        *(float2*)(out + (size_t)oe * 2) = o;
    }
}

// ---------------------------------------------------------------------------
extern "C" void kernel_launch(void* const* d_in, const int* in_sizes, int n_in,
                              void* d_out, int out_size, void* d_ws, size_t ws_size,
                              hipStream_t stream) {
    // ws layout (bytes):
    //   ea       : 0           .. 128,000,000  (f16 E*128, SORTED order)
    //   hf16     : 128,000,000 .. 140,800,000
    //   agg16/xc : 140,800,000 .. 153,600,000  (xc dead after node_lin)
    //   eord     : 153,600,000 .. 155,600,000
    //   off      : 155,600,000 .. 155,800,064
    //   cntcur   : 155,800,064 .. 156,000,064
    //   bsum     : 156,000,064 .. 156,001,088
    //   bpre     : 156,001,088 .. 156,002,112
    //   ssrc     : 156,002,176 .. 158,002,176
    //   sdst     : 158,002,176 .. 160,002,176
    //   eattr16  : 166,400,000 .. 182,400,000  (dead after edge_lin;
    //              overlays z2 166.4-179.2M and tn head 179.2-182.4M)
    //   z2       : 166,400,000 .. 179,200,000
    //   tn       : 179,200,000 .. 192,000,000
    //   wbuf     : 192,000,000 .. 192,475,136
    //   stats    : 192,475,136 .. 192,476,160
    //   prm      : 192,476,160 .. 193,425,796
    //   eix      : 193,425,920 .. 197,425,920
    //   flags    : 197,425,920 .. 197,425,936
    const size_t WS_NEED = 197425936ULL;
    if (ws_size < WS_NEED) {
        hipMemsetAsync(d_out, 0, (size_t)out_size * 4, stream);
        return;
    }
    char* ws = (char*)d_ws;
    f16* ea = (f16*)(ws);
    f16* hf16 = (f16*)(ws + 128000000LL);
    f16* agg16 = (f16*)(ws + 140800000LL);
    f16* xc = (f16*)(ws + 140800000LL);
    int* eord = (int*)(ws + 153600000LL);
    int* off = (int*)(ws + 155600000LL);
    int* cntcur = (int*)(ws + 155800064LL);
    int* bsum = (int*)(ws + 156000064LL);
    int* bpre = (int*)(ws + 156001088LL);
    int* ssrc = (int*)(ws + 156002176LL);
    int* sdst = (int*)(ws + 158002176LL);
    f16* eattr16 = (f16*)(ws + 166400000LL);
    f16* z2 = (f16*)(ws + 166400000LL);
    f16* tn = (f16*)(ws + 179200000LL);
    f16* wbuf = (f16*)(ws + 192000000LL);
    float* stats = (float*)(ws + 192475136LL);
    float* prm = (float*)(ws + 192476160LL);
    int* eix = (int*)(ws + 193425920LL);
    int* flags = (int*)(ws + 197425920LL);
    float* out = (float*)d_out;

    k_detect<<<1, 256, 0, stream>>>((const unsigned int*)d_in[2],
                                    (const int*)d_in[22], flags);
    k_cvt<<<6250, 256, 0, stream>>>(d_in[0], xc, 1600000, flags);
    k_cvt<<<7813, 256, 0, stream>>>(d_in[1], eattr16, 2000000, flags);
    k_cvt_prm<<<928, 256, 0, stream>>>(
        d_in[2], d_in[3], d_in[4], d_in[5], d_in[6], d_in[7], d_in[8], d_in[9],
        d_in[10], d_in[11], d_in[12], d_in[13], d_in[14], d_in[15], d_in[16],
        d_in[17], d_in[18], d_in[19], d_in[20], d_in[21], prm, flags);
    k_cvt_idx<<<3907, 256, 0, stream>>>((const int*)d_in[22], eix, flags);

    // CSR build + sorted index arrays (before node/edge linear so edge_lin
    // can write ea in sorted order).
    hipMemsetAsync(cntcur, 0, NN * 4, stream);
    k_hist<<<1954, 256, 0, stream>>>(eix, cntcur);
    k_scanA<<<196, 256, 0, stream>>>(cntcur, bsum);
    k_scanB<<<1, 256, 0, stream>>>(bsum, bpre, off);
    k_scanC<<<196, 256, 0, stream>>>(cntcur, bpre, off, cntcur);
    k_scatter<<<1954, 256, 0, stream>>>(eix, cntcur, eord);
    k_gidx<<<1954, 256, 0, stream>>>(eix, eord, ssrc, sdst);

    k_prep<<<928, 256, 0, stream>>>(prm, wbuf);
    k_node_lin<<<391, 256, 0, stream>>>(xc, wbuf, prm + P_NODE_B, hf16);
    k_edge_lin<<<7813, 256, 0, stream>>>(eattr16, prm + P_EDGE_W, prm + P_EDGE_B,
                                         eord, ea);

    for (int l = 0; l < 2; ++l) {
        hipMemsetAsync(stats, 0, 1024, stream);
        k_agg<<<12500, 256, 0, stream>>>(ea, hf16, ssrc, off, agg16);
        k_conv1<<<391, 256, 0, stream>>>(hf16, agg16, wbuf + (1 + l) * 16384,
                                         prm + P_CONV_B1 + l * HD, tn);
        k_conv2<<<391, 256, 0, stream>>>(tn, wbuf + (3 + l) * 16384,
                                         prm + P_CONV_B2 + l * HD, z2, stats);
        k_bn<<<6250, 256, 0, stream>>>(z2, stats, prm + P_GAMMA + l * HD,
                                       prm + P_BETA + l * HD, hf16);
        k_emlp<<<3907, 256, 0, stream>>>(hf16, ssrc, sdst,
                                         wbuf + (5 + l * 3) * 16384,
                                         prm + P_EMLP_B1 + l * HD,
                                         wbuf + (11 + l) * 16384,
                                         prm + P_EMLP_B2 + l * HD, ea);
    }
    k_readout<<<1954, 256, 0, stream>>>(hf16, ea, ssrc, sdst, eord,
                                        wbuf + 13 * 16384,
                                        prm + P_MLP_B1, prm + P_MLP_W2,
                                        prm + P_MLP_B2, prm + P_MLP_W3,
                                        prm + P_MLP_B3, out);
}